// Round 1
// 377.044 us; speedup vs baseline: 1.1437x; 1.1437x over previous
//
#include <hip/hip_runtime.h>
#include <hip/hip_bf16.h>
#include <stdint.h>

typedef __bf16 bf16x8 __attribute__((ext_vector_type(8)));
typedef float f32x4 __attribute__((ext_vector_type(4)));

static constexpr int T_SEQ  = 384;
static constexpr int NNEUR  = 128;
static constexpr int DMODEL = 512;
static constexpr int NROWS  = NNEUR * T_SEQ;   // 49152
static constexpr float ROPE_C = 0.8304820237218406f;  // log2(10000)/16

__device__ __forceinline__ float bf2f(unsigned short u) {
  union { unsigned int i; float f; } x; x.i = ((unsigned int)u) << 16; return x.f;
}
__device__ __forceinline__ unsigned short f2bf(float f) {
  union { float f; unsigned int i; } x; x.f = f;
  unsigned int i = x.i;
  i += 0x7FFFu + ((i >> 16) & 1u);   // RNE
  return (unsigned short)(i >> 16);
}
__device__ __forceinline__ float fast_exp2(float x) {
#if __has_builtin(__builtin_amdgcn_exp2f)
  return __builtin_amdgcn_exp2f(x);
#else
  return exp2f(x);
#endif
}

// async global->LDS, 16B per lane; LDS dest = wave-uniform base + lane*16
__device__ __forceinline__ void async_copy16(const unsigned short* g, unsigned short* l) {
  auto gp = reinterpret_cast<const __attribute__((address_space(1))) unsigned int*>(
      reinterpret_cast<uintptr_t>(g));
  auto lp = reinterpret_cast<__attribute__((address_space(3))) unsigned int*>(
      reinterpret_cast<uintptr_t>(l));
  __builtin_amdgcn_global_load_lds(gp, lp, 16, 0, 0);
}

// ------------------------------------------------------------------
// weights fp32 -> bf16
// ------------------------------------------------------------------
__global__ __launch_bounds__(256) void cvt_w_kernel(
    const float* __restrict__ w0, const float* __restrict__ w1,
    const float* __restrict__ w2, const float* __restrict__ w3,
    unsigned short* __restrict__ o0, unsigned short* __restrict__ o1,
    unsigned short* __restrict__ o2, unsigned short* __restrict__ o3)
{
  const float* w; unsigned short* o;
  switch (blockIdx.y) {
    case 0:  w = w0; o = o0; break;
    case 1:  w = w1; o = o1; break;
    case 2:  w = w2; o = o2; break;
    default: w = w3; o = o3; break;
  }
  int i = (blockIdx.x * 256 + threadIdx.x) * 4;
  float4 v = *reinterpret_cast<const float4*>(w + i);
  union { unsigned short u[4]; uint2 v2; } p;
  p.u[0] = f2bf(v.x); p.u[1] = f2bf(v.y); p.u[2] = f2bf(v.z); p.u[3] = f2bf(v.w);
  *reinterpret_cast<uint2*>(o + i) = p.v2;
}

// rope table: tab[t*16+i] = (sin, cos) of t * 10000^(-i/16)
__global__ __launch_bounds__(256) void rope_tab_kernel(float2* __restrict__ tab) {
  int idx = blockIdx.x * 256 + threadIdx.x;   // 6144
  int t = idx >> 4, i = idx & 15;
  float ang = (float)t * exp2f(-(float)i * ROPE_C);
  float s, c; sincosf(ang, &s, &c);
  tab[idx] = make_float2(s, c);
}

// ------------------------------------------------------------------
// RMSNorm: x[t][n][d] fp32 -> xt_bf[n][t][d] bf16 (also the residual)
// ------------------------------------------------------------------
__global__ __launch_bounds__(256) void rmsnorm_kernel(
    const float* __restrict__ x, const float* __restrict__ nw,
    unsigned short* __restrict__ xt)
{
  int wave = threadIdx.x >> 6, lane = threadIdx.x & 63;
  int rid = blockIdx.x * 4 + wave;       // rid = t*128 + n
  int t = rid >> 7, n = rid & 127;
  const float* row = x + (size_t)rid * DMODEL;
  float4 v0 = *reinterpret_cast<const float4*>(row + lane * 8);
  float4 v1 = *reinterpret_cast<const float4*>(row + lane * 8 + 4);
  float ss = v0.x*v0.x + v0.y*v0.y + v0.z*v0.z + v0.w*v0.w
           + v1.x*v1.x + v1.y*v1.y + v1.z*v1.z + v1.w*v1.w;
  #pragma unroll
  for (int off = 32; off; off >>= 1) ss += __shfl_xor(ss, off);
  float sc = rsqrtf(ss * (1.0f / DMODEL) + 1e-6f);
  float4 w0 = *reinterpret_cast<const float4*>(nw + lane * 8);
  float4 w1 = *reinterpret_cast<const float4*>(nw + lane * 8 + 4);
  union { unsigned short u[8]; uint4 v; } p;
  p.u[0] = f2bf(v0.x * sc * w0.x); p.u[1] = f2bf(v0.y * sc * w0.y);
  p.u[2] = f2bf(v0.z * sc * w0.z); p.u[3] = f2bf(v0.w * sc * w0.w);
  p.u[4] = f2bf(v1.x * sc * w1.x); p.u[5] = f2bf(v1.y * sc * w1.y);
  p.u[6] = f2bf(v1.z * sc * w1.z); p.u[7] = f2bf(v1.w * sc * w1.w);
  *reinterpret_cast<uint4*>(xt + ((size_t)n * T_SEQ + t) * DMODEL + lane * 8) = p.v;
}

// ------------------------------------------------------------------
// GEMM: D[m][n] = sum_k A[m][k]*B[n][k], bf16 in, fp32 acc.
// 256x128 tile, BK=64, 512 threads / 8 waves (4m x 2n), 16x16x32 MFMA,
// global_load_lds staging with XOR chunk swizzle.
// XCD-aware chunked block swizzle: column-siblings of an A row-panel
// land on the same XCD so the panel is fetched once per XCD (L2 reuse).
// MODE 0: fp32 row-major store (out = y Wo^T)
// MODE 2: bf16 row-major store + table RoPE; C covers q|k sections (n0>>9)
// MODE 3: bf16 transposed + k-permuted store -> vt[nn][dout][kperm(t)]
// ------------------------------------------------------------------
template <int MODE, typename OutT>
__global__ __launch_bounds__(512, 4) void gemm_k(
    const unsigned short* __restrict__ A,
    const unsigned short* __restrict__ B,
    OutT* __restrict__ C,
    const float2* __restrict__ tab)
{
  __shared__ alignas(16) unsigned short Sh[384 * 64];   // rows 0-255 A, 256-383 B
  const int tid  = threadIdx.x;
  const int wave = tid >> 6, lane = tid & 63;
  const int l15  = lane & 15, quad = lane >> 4;
  const int wm = (wave >> 1) * 64, wn = (wave & 1) * 64;

  // XCD-aware chunked swizzle (bijective: NB % 8 == 0, chunk % GX == 0)
  constexpr int GX = (MODE == 2) ? 8 : (MODE == 3) ? 2 : 4;
  constexpr int GY = (MODE == 3) ? 384 : 192;
  constexpr int NB = GX * GY;
  constexpr int CH = NB / 8;
  const int lin = (int)blockIdx.y * GX + (int)blockIdx.x;
  const int swz = (lin & 7) * CH + (lin >> 3);
  const int bx  = swz % GX, by = swz / GX;

  size_t m0; int n0;
  if constexpr (MODE == 3) { m0 = (size_t)bx * 256; n0 = by * 128; }
  else                     { m0 = (size_t)by * 256; n0 = bx * 128; }

  const int srow  = tid >> 3;                       // 0..63
  const int schunk = (tid & 7) ^ (srow & 7);        // swizzled global chunk
  const unsigned short* ga = A + (m0 + srow) * 512 + schunk * 8;
  const unsigned short* gb = B + ((size_t)n0 + srow) * 512 + schunk * 8;
  unsigned short* ls = &Sh[tid * 8];

  f32x4 acc[4][4] = {};
  for (int k0 = 0; k0 < 512; k0 += 64) {
    #pragma unroll
    for (int ra = 0; ra < 4; ++ra)
      async_copy16(ga + (size_t)ra * 32768 + k0, ls + ra * 4096);
    #pragma unroll
    for (int rb = 0; rb < 2; ++rb)
      async_copy16(gb + (size_t)rb * 32768 + k0, ls + (4 + rb) * 4096);
    __syncthreads();
    #pragma unroll
    for (int kc = 0; kc < 2; ++kc) {
      const int pc = ((kc * 4 + quad) ^ (l15 & 7)) * 8;
      bf16x8 a[4], b[4];
      #pragma unroll
      for (int i = 0; i < 4; ++i)
        a[i] = *reinterpret_cast<const bf16x8*>(&Sh[(wm + i * 16 + l15) * 64 + pc]);
      #pragma unroll
      for (int j = 0; j < 4; ++j)
        b[j] = *reinterpret_cast<const bf16x8*>(&Sh[(256 + wn + j * 16 + l15) * 64 + pc]);
      #pragma unroll
      for (int i = 0; i < 4; ++i)
        #pragma unroll
        for (int j = 0; j < 4; ++j)
          acc[i][j] = __builtin_amdgcn_mfma_f32_16x16x32_bf16(a[i], b[j], acc[i][j], 0, 0, 0);
    }
    __syncthreads();
  }

  // ---- epilogue ----
  if constexpr (MODE == 3) {
    // element: (dout = m-row, xtrow = n-col). store vt[nn][dout][kperm(t)]
    #pragma unroll
    for (int j = 0; j < 4; ++j) {
      int xbase = n0 + wn + j * 16;            // multiple of 16
      int nn    = xbase / 384;
      int bloc  = xbase - nn * 384;
      int off64 = (bloc >> 6) * 64 + ((bloc >> 4) & 3);   // + l15*4 gives k'
      #pragma unroll
      for (int i = 0; i < 4; ++i)
        #pragma unroll
        for (int r = 0; r < 4; ++r) {
          int dout = (int)m0 + wm + i * 16 + quad * 4 + r;
          C[((size_t)nn * 512 + dout) * 384 + off64 + l15 * 4] = f2bf(acc[i][j][r]);
        }
    }
  } else {
    OutT* Cb = C;
    int ncol0 = n0 + wn;
    if constexpr (MODE == 2) {
      int sec = n0 >> 9;                        // 0=q, 1=k
      Cb = C + (size_t)sec * NROWS * 512;
      ncol0 = (n0 & 511) + wn;
    }
    #pragma unroll
    for (int i = 0; i < 4; ++i) {
      #pragma unroll
      for (int r = 0; r < 4; ++r) {
        size_t grow = m0 + wm + i * 16 + quad * 4 + r;
        int t = (int)(grow % 384);
        #pragma unroll
        for (int j = 0; j < 4; ++j) {
          float v = acc[i][j][r];
          int col = ncol0 + j * 16 + l15;
          if constexpr (MODE == 2) {
            if (((ncol0 + j * 16) & 63) < 32) {   // rotary half (wave-uniform)
              float part = __shfl_xor(v, 1);
              float2 scv = tab[t * 16 + ((col & 63) >> 1)];
              v = (l15 & 1) ? (part * scv.x + v * scv.y)
                            : (v * scv.y - part * scv.x);
            }
            Cb[grow * 512 + col] = f2bf(v);
          } else {
            Cb[grow * 512 + col] = v;   // fp32
          }
        }
      }
    }
  }
}

// ------------------------------------------------------------------
// Flash attention. Q/K pre-RoPE'd; V pre-transposed AND k-permuted
// (vt[n][d][k'], k' = (t&15)*4 + (t>>4) within each 64-tile).
// Fixed-max exp2 softmax (no online max), deferred lsum reduction.
// XCD-swizzled so all qt-blocks of one (h,n) share an XCD's L2 (K/V reuse).
// ------------------------------------------------------------------
__global__ __launch_bounds__(256, 4) void attn_kernel(
    const unsigned short* __restrict__ qb,   // [n][t][512]
    const unsigned short* __restrict__ kb,   // [n][t][512]
    const unsigned short* __restrict__ vt,   // [n][512][384] (k-permuted)
    const unsigned short* __restrict__ xt,   // residual [n][t][512]
    const int* __restrict__ pad,             // [128]
    unsigned short* __restrict__ y)          // [t][n][512]
{
  // grid = (6, 8, 128) -> 6144 blocks; chunk = 768 (divisible by 6 and 48)
  const int lin = (int)blockIdx.x + 6 * ((int)blockIdx.y + 8 * (int)blockIdx.z);
  const int swz = (lin & 7) * 768 + (lin >> 3);
  const int qt  = swz % 6;          // 0..5
  const int rem = swz / 6;
  const int h   = rem & 7;          // 0..7
  const int n   = rem >> 3;         // 0..127
  __shared__ alignas(16) unsigned short Qs[64 * 64];
  __shared__ alignas(16) unsigned short Ks[64 * 64];
  __shared__ alignas(16) unsigned short VTs[64 * 64];
  __shared__ alignas(16) unsigned short Ps[4][16][72];

  const int tid  = threadIdx.x;
  const int wave = tid >> 6, lane = tid & 63;
  const int l15  = lane & 15, quad = lane >> 4;
  const int lrow = lane >> 3, lchunk = (lane & 7) ^ ((lane >> 3) & 7);
  const float C2 = 0.18033688011112042f;     // 0.125 * log2(e)

  const unsigned short* gq =
      qb + ((size_t)n * T_SEQ + qt * 64 + wave * 16 + lrow) * 512 + h * 64 + lchunk * 8;
  async_copy16(gq,           &Qs[(wave * 16) * 64]);
  async_copy16(gq + 8 * 512, &Qs[(wave * 16 + 8) * 64]);

  const unsigned short* gk0 =
      kb + ((size_t)n * T_SEQ + wave * 16 + lrow) * 512 + h * 64 + lchunk * 8;
  const unsigned short* gv0 =
      vt + ((size_t)n * 512 + h * 64 + wave * 16 + lrow) * 384 + lchunk * 8;

  float lsum[4] = {0.f, 0.f, 0.f, 0.f};
  f32x4 oacc[4] = {};

  for (int kt = 0; kt <= qt; ++kt) {
    async_copy16(gk0 + (size_t)(kt * 64) * 512,     &Ks[(wave * 16) * 64]);
    async_copy16(gk0 + (size_t)(kt * 64 + 8) * 512, &Ks[(wave * 16 + 8) * 64]);
    async_copy16(gv0 + kt * 64,                     &VTs[(wave * 16) * 64]);
    async_copy16(gv0 + kt * 64 + 8 * 384,           &VTs[(wave * 16 + 8) * 64]);
    __syncthreads();

    // ---- S = Q K^T ----
    f32x4 sc4[4] = {};
    #pragma unroll
    for (int kc = 0; kc < 2; ++kc) {
      const int pc = ((kc * 4 + quad) ^ (l15 & 7)) * 8;
      bf16x8 aq = *reinterpret_cast<const bf16x8*>(&Qs[(wave * 16 + l15) * 64 + pc]);
      #pragma unroll
      for (int tc = 0; tc < 4; ++tc) {
        bf16x8 bk = *reinterpret_cast<const bf16x8*>(&Ks[(tc * 16 + l15) * 64 + pc]);
        sc4[tc] = __builtin_amdgcn_mfma_f32_16x16x32_bf16(aq, bk, sc4[tc], 0, 0, 0);
      }
    }
    // ---- fixed-max exp2 softmax ----
    const bool diag = (kt == qt);
    float ps[4][4];
    #pragma unroll
    for (int tc = 0; tc < 4; ++tc)
      #pragma unroll
      for (int r = 0; r < 4; ++r) {
        float p = fast_exp2(sc4[tc][r] * C2 - 16.0f);
        if (diag && (tc * 16 + l15 > wave * 16 + quad * 4 + r)) p = 0.f;
        lsum[r] += p;
        ps[tc][r] = p;
      }
    // ---- pack P (trunc->bf16) into k'-permuted LDS: k' = l15*4 + tc ----
    #pragma unroll
    for (int r = 0; r < 4; ++r) {
      union { float f; unsigned int u; } a0, a1, a2, a3;
      a0.f = ps[0][r]; a1.f = ps[1][r]; a2.f = ps[2][r]; a3.f = ps[3][r];
      uint2 pk;
      pk.x = (a1.u & 0xffff0000u) | (a0.u >> 16);
      pk.y = (a3.u & 0xffff0000u) | (a2.u >> 16);
      *reinterpret_cast<uint2*>(&Ps[wave][quad * 4 + r][l15 * 4]) = pk;
    }
    // ---- O += P V (both sides k'-permuted) ----
    #pragma unroll
    for (int kc = 0; kc < 2; ++kc) {
      const int pc = ((kc * 4 + quad) ^ (l15 & 7)) * 8;
      bf16x8 ap = *reinterpret_cast<const bf16x8*>(&Ps[wave][l15][kc * 32 + quad * 8]);
      #pragma unroll
      for (int dt = 0; dt < 4; ++dt) {
        bf16x8 bv = *reinterpret_cast<const bf16x8*>(&VTs[(dt * 16 + l15) * 64 + pc]);
        oacc[dt] = __builtin_amdgcn_mfma_f32_16x16x32_bf16(ap, bv, oacc[dt], 0, 0, 0);
      }
    }
    __syncthreads();
  }

  // ---- lsum reduce + epilogue: mask + residual, write y[t][n][d] ----
  float inv[4];
  #pragma unroll
  for (int r = 0; r < 4; ++r) {
    float l = lsum[r];
    l += __shfl_xor(l, 1);
    l += __shfl_xor(l, 2);
    l += __shfl_xor(l, 4);
    l += __shfl_xor(l, 8);
    inv[r] = 1.0f / l;
  }
  bool valid = (pad[n] != 0);
  #pragma unroll
  for (int dt = 0; dt < 4; ++dt)
    #pragma unroll
    for (int r = 0; r < 4; ++r) {
      int tq = qt * 64 + wave * 16 + quad * 4 + r;
      int d  = h * 64 + dt * 16 + l15;
      float val = valid ? (oacc[dt][r] * inv[r]) : 0.f;
      float res = bf2f(xt[((size_t)n * T_SEQ + tq) * 512 + d]);
      y[((size_t)tq * NNEUR + n) * 512 + d] = f2bf(val + res);
    }
}

// ------------------------------------------------------------------
extern "C" void kernel_launch(void* const* d_in, const int* in_sizes, int n_in,
                              void* d_out, int out_size, void* d_ws, size_t ws_size,
                              hipStream_t stream) {
  const float* x   = (const float*)d_in[0];
  const int*   pad = (const int*)d_in[1];
  const float* nw  = (const float*)d_in[2];
  const float* wq  = (const float*)d_in[3];
  const float* wk  = (const float*)d_in[4];
  const float* wv  = (const float*)d_in[5];
  const float* wo  = (const float*)d_in[6];
  float* out = (float*)d_out;

  char* ws = (char*)d_ws;
  size_t off = 0;
  auto alloc = [&](size_t bytes) { void* p = ws + off; off += (bytes + 255) & ~(size_t)255; return p; };
  const size_t WELEM  = (size_t)512 * 512;        // elements per weight
  const size_t MBYTES = (size_t)NROWS * 512 * 2;
  unsigned short* wqkv_bf = (unsigned short*)alloc(WELEM * 3 * 2);
  unsigned short* wo_bf   = (unsigned short*)alloc(WELEM * 2);
  float2*         rtab    = (float2*)alloc(384 * 16 * sizeof(float2));
  unsigned short* xt_bf   = (unsigned short*)alloc(MBYTES);
  unsigned short* qk_buf  = (unsigned short*)alloc(MBYTES * 2);
  unsigned short* vt_buf  = (unsigned short*)alloc(MBYTES);
  unsigned short* y_buf   = (unsigned short*)alloc(MBYTES);

  cvt_w_kernel<<<dim3(256, 4), 256, 0, stream>>>(
      wq, wk, wv, wo,
      wqkv_bf, wqkv_bf + WELEM, wqkv_bf + 2 * WELEM, wo_bf);
  rope_tab_kernel<<<24, 256, 0, stream>>>(rtab);
  rmsnorm_kernel<<<NROWS / 4, 256, 0, stream>>>(x, nw, xt_bf);
  // fused Q|K GEMM (+RoPE): grid x = column block (8 -> n0 in [0,1024))
  gemm_k<2, unsigned short><<<dim3(8, NROWS / 256), 512, 0, stream>>>(
      xt_bf, wqkv_bf, qk_buf, rtab);
  // V^T (k-permuted): A = wv (512 rows), B = xt
  gemm_k<3, unsigned short><<<dim3(2, NROWS / 128), 512, 0, stream>>>(
      wqkv_bf + 2 * WELEM, xt_bf, vt_buf, nullptr);
  attn_kernel<<<dim3(6, 8, 128), 256, 0, stream>>>(
      qk_buf, qk_buf + (size_t)NROWS * 512, vt_buf, xt_bf, pad, y_buf);
  // out = y Wo^T (fp32)
  gemm_k<0, float><<<dim3(4, NROWS / 256), 512, 0, stream>>>(
      y_buf, wo_bf, out, nullptr);
}

// Round 2
// 358.215 us; speedup vs baseline: 1.2038x; 1.0526x over previous
//
#include <hip/hip_runtime.h>
#include <hip/hip_bf16.h>
#include <stdint.h>

typedef __bf16 bf16x8 __attribute__((ext_vector_type(8)));
typedef float f32x4 __attribute__((ext_vector_type(4)));

static constexpr int T_SEQ  = 384;
static constexpr int NNEUR  = 128;
static constexpr int DMODEL = 512;
static constexpr int NROWS  = NNEUR * T_SEQ;   // 49152
static constexpr float ROPE_C = 0.8304820237218406f;  // log2(10000)/16

__device__ __forceinline__ float bf2f(unsigned short u) {
  union { unsigned int i; float f; } x; x.i = ((unsigned int)u) << 16; return x.f;
}
__device__ __forceinline__ unsigned short f2bf(float f) {
  union { float f; unsigned int i; } x; x.f = f;
  unsigned int i = x.i;
  i += 0x7FFFu + ((i >> 16) & 1u);   // RNE
  return (unsigned short)(i >> 16);
}
__device__ __forceinline__ float fast_exp2(float x) {
#if __has_builtin(__builtin_amdgcn_exp2f)
  return __builtin_amdgcn_exp2f(x);
#else
  return exp2f(x);
#endif
}

// async global->LDS, 16B per lane; LDS dest = wave-uniform base + lane*16
__device__ __forceinline__ void async_copy16(const unsigned short* g, unsigned short* l) {
  auto gp = reinterpret_cast<const __attribute__((address_space(1))) unsigned int*>(
      reinterpret_cast<uintptr_t>(g));
  auto lp = reinterpret_cast<__attribute__((address_space(3))) unsigned int*>(
      reinterpret_cast<uintptr_t>(l));
  __builtin_amdgcn_global_load_lds(gp, lp, 16, 0, 0);
}

// ------------------------------------------------------------------
// weights fp32 -> bf16
// ------------------------------------------------------------------
__global__ __launch_bounds__(256) void cvt_w_kernel(
    const float* __restrict__ w0, const float* __restrict__ w1,
    const float* __restrict__ w2, const float* __restrict__ w3,
    unsigned short* __restrict__ o0, unsigned short* __restrict__ o1,
    unsigned short* __restrict__ o2, unsigned short* __restrict__ o3)
{
  const float* w; unsigned short* o;
  switch (blockIdx.y) {
    case 0:  w = w0; o = o0; break;
    case 1:  w = w1; o = o1; break;
    case 2:  w = w2; o = o2; break;
    default: w = w3; o = o3; break;
  }
  int i = (blockIdx.x * 256 + threadIdx.x) * 4;
  float4 v = *reinterpret_cast<const float4*>(w + i);
  union { unsigned short u[4]; uint2 v2; } p;
  p.u[0] = f2bf(v.x); p.u[1] = f2bf(v.y); p.u[2] = f2bf(v.z); p.u[3] = f2bf(v.w);
  *reinterpret_cast<uint2*>(o + i) = p.v2;
}

// rope table: tab[t*16+i] = (sin, cos) of t * 10000^(-i/16)
__global__ __launch_bounds__(256) void rope_tab_kernel(float2* __restrict__ tab) {
  int idx = blockIdx.x * 256 + threadIdx.x;   // 6144
  int t = idx >> 4, i = idx & 15;
  float ang = (float)t * exp2f(-(float)i * ROPE_C);
  float s, c; sincosf(ang, &s, &c);
  tab[idx] = make_float2(s, c);
}

// ------------------------------------------------------------------
// RMSNorm: x[t][n][d] fp32 -> xt_bf[n][t][d] bf16 (also the residual)
// ------------------------------------------------------------------
__global__ __launch_bounds__(256) void rmsnorm_kernel(
    const float* __restrict__ x, const float* __restrict__ nw,
    unsigned short* __restrict__ xt)
{
  int wave = threadIdx.x >> 6, lane = threadIdx.x & 63;
  int rid = blockIdx.x * 4 + wave;       // rid = t*128 + n
  int t = rid >> 7, n = rid & 127;
  const float* row = x + (size_t)rid * DMODEL;
  float4 v0 = *reinterpret_cast<const float4*>(row + lane * 8);
  float4 v1 = *reinterpret_cast<const float4*>(row + lane * 8 + 4);
  float ss = v0.x*v0.x + v0.y*v0.y + v0.z*v0.z + v0.w*v0.w
           + v1.x*v1.x + v1.y*v1.y + v1.z*v1.z + v1.w*v1.w;
  #pragma unroll
  for (int off = 32; off; off >>= 1) ss += __shfl_xor(ss, off);
  float sc = rsqrtf(ss * (1.0f / DMODEL) + 1e-6f);
  float4 w0 = *reinterpret_cast<const float4*>(nw + lane * 8);
  float4 w1 = *reinterpret_cast<const float4*>(nw + lane * 8 + 4);
  union { unsigned short u[8]; uint4 v; } p;
  p.u[0] = f2bf(v0.x * sc * w0.x); p.u[1] = f2bf(v0.y * sc * w0.y);
  p.u[2] = f2bf(v0.z * sc * w0.z); p.u[3] = f2bf(v0.w * sc * w0.w);
  p.u[4] = f2bf(v1.x * sc * w1.x); p.u[5] = f2bf(v1.y * sc * w1.y);
  p.u[6] = f2bf(v1.z * sc * w1.z); p.u[7] = f2bf(v1.w * sc * w1.w);
  *reinterpret_cast<uint4*>(xt + ((size_t)n * T_SEQ + t) * DMODEL + lane * 8) = p.v;
}

// ------------------------------------------------------------------
// GEMM: D[m][n] = sum_k A[m][k]*B[n][k], bf16 in, fp32 acc.
// 256x128 tile, BK=64, 512 threads / 8 waves (4m x 2n), 16x16x32 MFMA,
// global_load_lds staging with XOR chunk swizzle.
// XCD-aware chunked block swizzle for A-panel L2 reuse.
// Pad-mask skip: tiles whose output belongs only to invalid neurons
// are dead (attn early-exits on them) -> return before any work.
// MODE 0: fp32 row-major store (out = y Wo^T)
// MODE 2: bf16 row-major store + table RoPE; C covers q|k sections (n0>>9)
// MODE 3: bf16 transposed + k-permuted store -> vt[nn][dout][kperm(t)]
// ------------------------------------------------------------------
template <int MODE, typename OutT>
__global__ __launch_bounds__(512, 4) void gemm_k(
    const unsigned short* __restrict__ A,
    const unsigned short* __restrict__ B,
    OutT* __restrict__ C,
    const float2* __restrict__ tab,
    const int* __restrict__ pad)
{
  __shared__ alignas(16) unsigned short Sh[384 * 64];   // rows 0-255 A, 256-383 B
  const int tid  = threadIdx.x;
  const int wave = tid >> 6, lane = tid & 63;
  const int l15  = lane & 15, quad = lane >> 4;
  const int wm = (wave >> 1) * 64, wn = (wave & 1) * 64;

  // XCD-aware chunked swizzle (bijective: NB % 8 == 0, chunk % GX == 0)
  constexpr int GX = (MODE == 2) ? 8 : (MODE == 3) ? 2 : 4;
  constexpr int GY = (MODE == 3) ? 384 : 192;
  constexpr int NB = GX * GY;
  constexpr int CH = NB / 8;
  const int lin = (int)blockIdx.y * GX + (int)blockIdx.x;
  const int swz = (lin & 7) * CH + (lin >> 3);
  const int bx  = swz % GX, by = swz / GX;

  size_t m0; int n0;
  if constexpr (MODE == 3) { m0 = (size_t)bx * 256; n0 = by * 128; }
  else                     { m0 = (size_t)by * 256; n0 = bx * 128; }

  // dead-tile skip (wave-uniform)
  if constexpr (MODE == 2) {
    int nfirst = (int)(m0 / 384);
    int nlast  = (int)((m0 + 255) / 384);
    if (pad[nfirst] == 0 && pad[nlast] == 0) return;
  }
  if constexpr (MODE == 3) {
    if (pad[n0 / 384] == 0) return;   // 128-col tile lies in one neuron
  }

  const int srow  = tid >> 3;                       // 0..63
  const int schunk = (tid & 7) ^ (srow & 7);        // swizzled global chunk
  const unsigned short* ga = A + (m0 + srow) * 512 + schunk * 8;
  const unsigned short* gb = B + ((size_t)n0 + srow) * 512 + schunk * 8;
  unsigned short* ls = &Sh[tid * 8];

  f32x4 acc[4][4] = {};
  for (int k0 = 0; k0 < 512; k0 += 64) {
    #pragma unroll
    for (int ra = 0; ra < 4; ++ra)
      async_copy16(ga + (size_t)ra * 32768 + k0, ls + ra * 4096);
    #pragma unroll
    for (int rb = 0; rb < 2; ++rb)
      async_copy16(gb + (size_t)rb * 32768 + k0, ls + (4 + rb) * 4096);
    __syncthreads();
    #pragma unroll
    for (int kc = 0; kc < 2; ++kc) {
      const int pc = ((kc * 4 + quad) ^ (l15 & 7)) * 8;
      bf16x8 a[4], b[4];
      #pragma unroll
      for (int i = 0; i < 4; ++i)
        a[i] = *reinterpret_cast<const bf16x8*>(&Sh[(wm + i * 16 + l15) * 64 + pc]);
      #pragma unroll
      for (int j = 0; j < 4; ++j)
        b[j] = *reinterpret_cast<const bf16x8*>(&Sh[(256 + wn + j * 16 + l15) * 64 + pc]);
      #pragma unroll
      for (int i = 0; i < 4; ++i)
        #pragma unroll
        for (int j = 0; j < 4; ++j)
          acc[i][j] = __builtin_amdgcn_mfma_f32_16x16x32_bf16(a[i], b[j], acc[i][j], 0, 0, 0);
    }
    __syncthreads();
  }

  // ---- epilogue ----
  if constexpr (MODE == 3) {
    // element: (dout = m-row, xtrow = n-col). store vt[nn][dout][kperm(t)]
    #pragma unroll
    for (int j = 0; j < 4; ++j) {
      int xbase = n0 + wn + j * 16;            // multiple of 16
      int nn    = xbase / 384;
      int bloc  = xbase - nn * 384;
      int off64 = (bloc >> 6) * 64 + ((bloc >> 4) & 3);   // + l15*4 gives k'
      #pragma unroll
      for (int i = 0; i < 4; ++i)
        #pragma unroll
        for (int r = 0; r < 4; ++r) {
          int dout = (int)m0 + wm + i * 16 + quad * 4 + r;
          C[((size_t)nn * 512 + dout) * 384 + off64 + l15 * 4] = f2bf(acc[i][j][r]);
        }
    }
  } else {
    OutT* Cb = C;
    int ncol0 = n0 + wn;
    if constexpr (MODE == 2) {
      int sec = n0 >> 9;                        // 0=q, 1=k
      Cb = C + (size_t)sec * NROWS * 512;
      ncol0 = (n0 & 511) + wn;
    }
    #pragma unroll
    for (int i = 0; i < 4; ++i) {
      #pragma unroll
      for (int r = 0; r < 4; ++r) {
        size_t grow = m0 + wm + i * 16 + quad * 4 + r;
        int t = (int)(grow % 384);
        #pragma unroll
        for (int j = 0; j < 4; ++j) {
          float v = acc[i][j][r];
          int col = ncol0 + j * 16 + l15;
          if constexpr (MODE == 2) {
            if (((ncol0 + j * 16) & 63) < 32) {   // rotary half (wave-uniform)
              float part = __shfl_xor(v, 1);
              float2 scv = tab[t * 16 + ((col & 63) >> 1)];
              v = (l15 & 1) ? (part * scv.x + v * scv.y)
                            : (v * scv.y - part * scv.x);
            }
            Cb[grow * 512 + col] = f2bf(v);
          } else {
            Cb[grow * 512 + col] = v;   // fp32
          }
        }
      }
    }
  }
}

// ------------------------------------------------------------------
// Flash attention. Q/K pre-RoPE'd; V pre-transposed AND k-permuted
// (vt[n][d][k'], k' = (t&15)*4 + (t>>4) within each 64-tile).
// Fixed-max exp2 softmax (no online max), deferred lsum reduction.
// XCD-swizzled so all qt-blocks of one (h,n) share an XCD's L2.
// Invalid neurons (pad==0): y = residual, no attention compute.
// ------------------------------------------------------------------
__global__ __launch_bounds__(256, 4) void attn_kernel(
    const unsigned short* __restrict__ qb,   // [n][t][512]
    const unsigned short* __restrict__ kb,   // [n][t][512]
    const unsigned short* __restrict__ vt,   // [n][512][384] (k-permuted)
    const unsigned short* __restrict__ xt,   // residual [n][t][512]
    const int* __restrict__ pad,             // [128]
    unsigned short* __restrict__ y)          // [t][n][512]
{
  // grid = (6, 8, 128) -> 6144 blocks; chunk = 768 (divisible by 6 and 48)
  const int lin = (int)blockIdx.x + 6 * ((int)blockIdx.y + 8 * (int)blockIdx.z);
  const int swz = (lin & 7) * 768 + (lin >> 3);
  const int qt  = swz % 6;          // 0..5
  const int rem = swz / 6;
  const int h   = rem & 7;          // 0..7
  const int n   = rem >> 3;         // 0..127

  const int tid  = threadIdx.x;

  if (pad[n] == 0) {
    // y = residual only (bf16 copy is exact). 64 rows x 64 cols per block.
    int tq = qt * 64 + (tid >> 2);
    int d  = h * 64 + (tid & 3) * 16;
    const uint4* src = reinterpret_cast<const uint4*>(
        &xt[((size_t)n * T_SEQ + tq) * 512 + d]);
    uint4* dst = reinterpret_cast<uint4*>(
        &y[((size_t)tq * NNEUR + n) * 512 + d]);
    dst[0] = src[0];
    dst[1] = src[1];
    return;
  }

  __shared__ alignas(16) unsigned short Qs[64 * 64];
  __shared__ alignas(16) unsigned short Ks[64 * 64];
  __shared__ alignas(16) unsigned short VTs[64 * 64];
  __shared__ alignas(16) unsigned short Ps[4][16][72];

  const int wave = tid >> 6, lane = tid & 63;
  const int l15  = lane & 15, quad = lane >> 4;
  const int lrow = lane >> 3, lchunk = (lane & 7) ^ ((lane >> 3) & 7);
  const float C2 = 0.18033688011112042f;     // 0.125 * log2(e)

  const unsigned short* gq =
      qb + ((size_t)n * T_SEQ + qt * 64 + wave * 16 + lrow) * 512 + h * 64 + lchunk * 8;
  async_copy16(gq,           &Qs[(wave * 16) * 64]);
  async_copy16(gq + 8 * 512, &Qs[(wave * 16 + 8) * 64]);

  const unsigned short* gk0 =
      kb + ((size_t)n * T_SEQ + wave * 16 + lrow) * 512 + h * 64 + lchunk * 8;
  const unsigned short* gv0 =
      vt + ((size_t)n * 512 + h * 64 + wave * 16 + lrow) * 384 + lchunk * 8;

  float lsum[4] = {0.f, 0.f, 0.f, 0.f};
  f32x4 oacc[4] = {};

  for (int kt = 0; kt <= qt; ++kt) {
    async_copy16(gk0 + (size_t)(kt * 64) * 512,     &Ks[(wave * 16) * 64]);
    async_copy16(gk0 + (size_t)(kt * 64 + 8) * 512, &Ks[(wave * 16 + 8) * 64]);
    async_copy16(gv0 + kt * 64,                     &VTs[(wave * 16) * 64]);
    async_copy16(gv0 + kt * 64 + 8 * 384,           &VTs[(wave * 16 + 8) * 64]);
    __syncthreads();

    // ---- S = Q K^T ----
    f32x4 sc4[4] = {};
    #pragma unroll
    for (int kc = 0; kc < 2; ++kc) {
      const int pc = ((kc * 4 + quad) ^ (l15 & 7)) * 8;
      bf16x8 aq = *reinterpret_cast<const bf16x8*>(&Qs[(wave * 16 + l15) * 64 + pc]);
      #pragma unroll
      for (int tc = 0; tc < 4; ++tc) {
        bf16x8 bk = *reinterpret_cast<const bf16x8*>(&Ks[(tc * 16 + l15) * 64 + pc]);
        sc4[tc] = __builtin_amdgcn_mfma_f32_16x16x32_bf16(aq, bk, sc4[tc], 0, 0, 0);
      }
    }
    // ---- fixed-max exp2 softmax ----
    const bool diag = (kt == qt);
    float ps[4][4];
    #pragma unroll
    for (int tc = 0; tc < 4; ++tc)
      #pragma unroll
      for (int r = 0; r < 4; ++r) {
        float p = fast_exp2(sc4[tc][r] * C2 - 16.0f);
        if (diag && (tc * 16 + l15 > wave * 16 + quad * 4 + r)) p = 0.f;
        lsum[r] += p;
        ps[tc][r] = p;
      }
    // ---- pack P (trunc->bf16) into k'-permuted LDS: k' = l15*4 + tc ----
    #pragma unroll
    for (int r = 0; r < 4; ++r) {
      union { float f; unsigned int u; } a0, a1, a2, a3;
      a0.f = ps[0][r]; a1.f = ps[1][r]; a2.f = ps[2][r]; a3.f = ps[3][r];
      uint2 pk;
      pk.x = (a1.u & 0xffff0000u) | (a0.u >> 16);
      pk.y = (a3.u & 0xffff0000u) | (a2.u >> 16);
      *reinterpret_cast<uint2*>(&Ps[wave][quad * 4 + r][l15 * 4]) = pk;
    }
    // ---- O += P V (both sides k'-permuted) ----
    #pragma unroll
    for (int kc = 0; kc < 2; ++kc) {
      const int pc = ((kc * 4 + quad) ^ (l15 & 7)) * 8;
      bf16x8 ap = *reinterpret_cast<const bf16x8*>(&Ps[wave][l15][kc * 32 + quad * 8]);
      #pragma unroll
      for (int dt = 0; dt < 4; ++dt) {
        bf16x8 bv = *reinterpret_cast<const bf16x8*>(&VTs[(dt * 16 + l15) * 64 + pc]);
        oacc[dt] = __builtin_amdgcn_mfma_f32_16x16x32_bf16(ap, bv, oacc[dt], 0, 0, 0);
      }
    }
    __syncthreads();
  }

  // ---- lsum reduce + epilogue: residual add, write y[t][n][d] ----
  float inv[4];
  #pragma unroll
  for (int r = 0; r < 4; ++r) {
    float l = lsum[r];
    l += __shfl_xor(l, 1);
    l += __shfl_xor(l, 2);
    l += __shfl_xor(l, 4);
    l += __shfl_xor(l, 8);
    inv[r] = 1.0f / l;
  }
  #pragma unroll
  for (int dt = 0; dt < 4; ++dt)
    #pragma unroll
    for (int r = 0; r < 4; ++r) {
      int tq = qt * 64 + wave * 16 + quad * 4 + r;
      int d  = h * 64 + dt * 16 + l15;
      float val = oacc[dt][r] * inv[r];
      float res = bf2f(xt[((size_t)n * T_SEQ + tq) * 512 + d]);
      y[((size_t)tq * NNEUR + n) * 512 + d] = f2bf(val + res);
    }
}

// ------------------------------------------------------------------
extern "C" void kernel_launch(void* const* d_in, const int* in_sizes, int n_in,
                              void* d_out, int out_size, void* d_ws, size_t ws_size,
                              hipStream_t stream) {
  const float* x   = (const float*)d_in[0];
  const int*   pad = (const int*)d_in[1];
  const float* nw  = (const float*)d_in[2];
  const float* wq  = (const float*)d_in[3];
  const float* wk  = (const float*)d_in[4];
  const float* wv  = (const float*)d_in[5];
  const float* wo  = (const float*)d_in[6];
  float* out = (float*)d_out;

  char* ws = (char*)d_ws;
  size_t off = 0;
  auto alloc = [&](size_t bytes) { void* p = ws + off; off += (bytes + 255) & ~(size_t)255; return p; };
  const size_t WELEM  = (size_t)512 * 512;        // elements per weight
  const size_t MBYTES = (size_t)NROWS * 512 * 2;
  unsigned short* wqkv_bf = (unsigned short*)alloc(WELEM * 3 * 2);
  unsigned short* wo_bf   = (unsigned short*)alloc(WELEM * 2);
  float2*         rtab    = (float2*)alloc(384 * 16 * sizeof(float2));
  unsigned short* xt_bf   = (unsigned short*)alloc(MBYTES);
  unsigned short* qk_buf  = (unsigned short*)alloc(MBYTES * 2);
  unsigned short* vt_buf  = (unsigned short*)alloc(MBYTES);
  unsigned short* y_buf   = (unsigned short*)alloc(MBYTES);

  cvt_w_kernel<<<dim3(256, 4), 256, 0, stream>>>(
      wq, wk, wv, wo,
      wqkv_bf, wqkv_bf + WELEM, wqkv_bf + 2 * WELEM, wo_bf);
  rope_tab_kernel<<<24, 256, 0, stream>>>(rtab);
  rmsnorm_kernel<<<NROWS / 4, 256, 0, stream>>>(x, nw, xt_bf);
  // fused Q|K GEMM (+RoPE): grid x = column block (8 -> n0 in [0,1024))
  gemm_k<2, unsigned short><<<dim3(8, NROWS / 256), 512, 0, stream>>>(
      xt_bf, wqkv_bf, qk_buf, rtab, pad);
  // V^T (k-permuted): A = wv (512 rows), B = xt
  gemm_k<3, unsigned short><<<dim3(2, NROWS / 128), 512, 0, stream>>>(
      wqkv_bf + 2 * WELEM, xt_bf, vt_buf, nullptr, pad);
  attn_kernel<<<dim3(6, 8, 128), 256, 0, stream>>>(
      qk_buf, qk_buf + (size_t)NROWS * 512, vt_buf, xt_bf, pad, y_buf);
  // out = y Wo^T (fp32)
  gemm_k<0, float><<<dim3(4, NROWS / 256), 512, 0, stream>>>(
      y_buf, wo_bf, out, nullptr, nullptr);
}

// Round 3
// 352.752 us; speedup vs baseline: 1.2224x; 1.0155x over previous
//
#include <hip/hip_runtime.h>
#include <hip/hip_bf16.h>
#include <stdint.h>

typedef __bf16 bf16x8 __attribute__((ext_vector_type(8)));
typedef float f32x4 __attribute__((ext_vector_type(4)));

static constexpr int T_SEQ  = 384;
static constexpr int NNEUR  = 128;
static constexpr int DMODEL = 512;
static constexpr int NROWS  = NNEUR * T_SEQ;   // 49152
static constexpr float ROPE_C = 0.8304820237218406f;  // log2(10000)/16

__device__ __forceinline__ float bf2f(unsigned short u) {
  union { unsigned int i; float f; } x; x.i = ((unsigned int)u) << 16; return x.f;
}
__device__ __forceinline__ unsigned short f2bf(float f) {
  union { float f; unsigned int i; } x; x.f = f;
  unsigned int i = x.i;
  i += 0x7FFFu + ((i >> 16) & 1u);   // RNE
  return (unsigned short)(i >> 16);
}
__device__ __forceinline__ float fast_exp2(float x) {
#if __has_builtin(__builtin_amdgcn_exp2f)
  return __builtin_amdgcn_exp2f(x);
#else
  return exp2f(x);
#endif
}

// async global->LDS, 16B per lane; LDS dest = wave-uniform base + lane*16
__device__ __forceinline__ void async_copy16(const unsigned short* g, unsigned short* l) {
  auto gp = reinterpret_cast<const __attribute__((address_space(1))) unsigned int*>(
      reinterpret_cast<uintptr_t>(g));
  auto lp = reinterpret_cast<__attribute__((address_space(3))) unsigned int*>(
      reinterpret_cast<uintptr_t>(l));
  __builtin_amdgcn_global_load_lds(gp, lp, 16, 0, 0);
}

// ------------------------------------------------------------------
// weights fp32 -> bf16
// ------------------------------------------------------------------
__global__ __launch_bounds__(256) void cvt_w_kernel(
    const float* __restrict__ w0, const float* __restrict__ w1,
    const float* __restrict__ w2, const float* __restrict__ w3,
    unsigned short* __restrict__ o0, unsigned short* __restrict__ o1,
    unsigned short* __restrict__ o2, unsigned short* __restrict__ o3)
{
  const float* w; unsigned short* o;
  switch (blockIdx.y) {
    case 0:  w = w0; o = o0; break;
    case 1:  w = w1; o = o1; break;
    case 2:  w = w2; o = o2; break;
    default: w = w3; o = o3; break;
  }
  int i = (blockIdx.x * 256 + threadIdx.x) * 4;
  float4 v = *reinterpret_cast<const float4*>(w + i);
  union { unsigned short u[4]; uint2 v2; } p;
  p.u[0] = f2bf(v.x); p.u[1] = f2bf(v.y); p.u[2] = f2bf(v.z); p.u[3] = f2bf(v.w);
  *reinterpret_cast<uint2*>(o + i) = p.v2;
}

// rope table: tab[t*16+i] = (sin, cos) of t * 10000^(-i/16)
__global__ __launch_bounds__(256) void rope_tab_kernel(float2* __restrict__ tab) {
  int idx = blockIdx.x * 256 + threadIdx.x;   // 6144
  int t = idx >> 4, i = idx & 15;
  float ang = (float)t * exp2f(-(float)i * ROPE_C);
  float s, c; sincosf(ang, &s, &c);
  tab[idx] = make_float2(s, c);
}

// ------------------------------------------------------------------
// RMSNorm: x[t][n][d] fp32 -> xt_bf[n][t][d] bf16 (also the residual)
// ------------------------------------------------------------------
__global__ __launch_bounds__(256) void rmsnorm_kernel(
    const float* __restrict__ x, const float* __restrict__ nw,
    unsigned short* __restrict__ xt)
{
  int wave = threadIdx.x >> 6, lane = threadIdx.x & 63;
  int rid = blockIdx.x * 4 + wave;       // rid = t*128 + n
  int t = rid >> 7, n = rid & 127;
  const float* row = x + (size_t)rid * DMODEL;
  float4 v0 = *reinterpret_cast<const float4*>(row + lane * 8);
  float4 v1 = *reinterpret_cast<const float4*>(row + lane * 8 + 4);
  float ss = v0.x*v0.x + v0.y*v0.y + v0.z*v0.z + v0.w*v0.w
           + v1.x*v1.x + v1.y*v1.y + v1.z*v1.z + v1.w*v1.w;
  #pragma unroll
  for (int off = 32; off; off >>= 1) ss += __shfl_xor(ss, off);
  float sc = rsqrtf(ss * (1.0f / DMODEL) + 1e-6f);
  float4 w0 = *reinterpret_cast<const float4*>(nw + lane * 8);
  float4 w1 = *reinterpret_cast<const float4*>(nw + lane * 8 + 4);
  union { unsigned short u[8]; uint4 v; } p;
  p.u[0] = f2bf(v0.x * sc * w0.x); p.u[1] = f2bf(v0.y * sc * w0.y);
  p.u[2] = f2bf(v0.z * sc * w0.z); p.u[3] = f2bf(v0.w * sc * w0.w);
  p.u[4] = f2bf(v1.x * sc * w1.x); p.u[5] = f2bf(v1.y * sc * w1.y);
  p.u[6] = f2bf(v1.z * sc * w1.z); p.u[7] = f2bf(v1.w * sc * w1.w);
  *reinterpret_cast<uint4*>(xt + ((size_t)n * T_SEQ + t) * DMODEL + lane * 8) = p.v;
}

// ------------------------------------------------------------------
// GEMM: D[m][n] = sum_k A[m][k]*B[n][k], bf16 in, fp32 acc.
// 256x128 tile, 512 threads / 8 waves (4m x 2n), 16x16x32 MFMA.
// BK=32 double-buffered 2-phase pipeline with RAW s_barrier + counted
// vmcnt(3): next-tile global_load_lds stays in flight across the
// barrier and its latency hides under the current tile's MFMA.
// XCD-aware chunked block swizzle for A-panel L2 reuse.
// Pad-mask skip for dead tiles (attn ignores invalid neurons).
// MODE 0: fp32 row-major store (out = y Wo^T)
// MODE 2: bf16 row-major store + table RoPE; C covers q|k sections (n0>>9)
// MODE 3: bf16 transposed + k-permuted store -> vt[nn][dout][kperm(t)]
// ------------------------------------------------------------------
template <int MODE, typename OutT>
__global__ __launch_bounds__(512, 4) void gemm_k(
    const unsigned short* __restrict__ A,
    const unsigned short* __restrict__ B,
    OutT* __restrict__ C,
    const float2* __restrict__ tab,
    const int* __restrict__ pad)
{
  // per buffer: A 256x32 (8192) + B 128x32 (4096) = 12288 elems; x2 = 48 KiB
  __shared__ alignas(16) unsigned short Sh[2][12288];
  const int tid  = threadIdx.x;
  const int wave = tid >> 6, lane = tid & 63;
  const int l15  = lane & 15, quad = lane >> 4;
  const int wm = (wave >> 1) * 64, wn = (wave & 1) * 64;

  // XCD-aware chunked swizzle (bijective: NB % 8 == 0, chunk % GX == 0)
  constexpr int GX = (MODE == 2) ? 8 : (MODE == 3) ? 2 : 4;
  constexpr int GY = (MODE == 3) ? 384 : 192;
  constexpr int NB = GX * GY;
  constexpr int CH = NB / 8;
  const int lin = (int)blockIdx.y * GX + (int)blockIdx.x;
  const int swz = (lin & 7) * CH + (lin >> 3);
  const int bx  = swz % GX, by = swz / GX;

  size_t m0; int n0;
  if constexpr (MODE == 3) { m0 = (size_t)bx * 256; n0 = by * 128; }
  else                     { m0 = (size_t)by * 256; n0 = bx * 128; }

  // dead-tile skip (wave-uniform) -- BEFORE any staging is issued
  if constexpr (MODE == 2) {
    int nfirst = (int)(m0 / 384);
    int nlast  = (int)((m0 + 255) / 384);
    if (pad[nfirst] == 0 && pad[nlast] == 0) return;
  }
  if constexpr (MODE == 3) {
    if (pad[n0 / 384] == 0) return;   // 128-col tile lies in one neuron
  }

  // staging geometry: thread covers row r4 (+128 for 2nd A copy), chunk c4
  const int r4 = tid >> 2;                 // 0..127
  const int c4 = tid & 3;
  const int gc = c4 ^ (r4 & 3);            // swizzled global chunk
  const unsigned short* ga = A + (m0 + r4) * 512 + gc * 8;
  const unsigned short* gb = B + ((size_t)n0 + r4) * 512 + gc * 8;

  // LDS->reg fragment chunk (unswizzle): row = ..+l15 so row&3 == l15&3
  const int pc = (quad ^ (l15 & 3)) * 8;

  auto STAGE = [&](int kk, int b) {
    const unsigned short* gak = ga + kk * 32;
    unsigned short* base = &Sh[b][0];
    async_copy16(gak,             base + tid * 8);          // A rows 0-127
    async_copy16(gak + 128 * 512, base + 4096 + tid * 8);   // A rows 128-255
    async_copy16(gb + kk * 32,    base + 8192 + tid * 8);   // B rows 0-127
  };

  f32x4 acc[4][4] = {};
  auto COMPUTE = [&](int b) {
    const unsigned short* base = &Sh[b][0];
    bf16x8 a[4], bb[4];
    #pragma unroll
    for (int i = 0; i < 4; ++i)
      a[i] = *reinterpret_cast<const bf16x8*>(&base[(wm + i * 16 + l15) * 32 + pc]);
    #pragma unroll
    for (int j = 0; j < 4; ++j)
      bb[j] = *reinterpret_cast<const bf16x8*>(&base[8192 + (wn + j * 16 + l15) * 32 + pc]);
    #pragma unroll
    for (int i = 0; i < 4; ++i)
      #pragma unroll
      for (int j = 0; j < 4; ++j)
        acc[i][j] = __builtin_amdgcn_mfma_f32_16x16x32_bf16(a[i], bb[j], acc[i][j], 0, 0, 0);
  };

  STAGE(0, 0);
  #pragma unroll 2
  for (int kk = 0; kk < 15; ++kk) {
    const int b = kk & 1;
    STAGE(kk + 1, b ^ 1);
    asm volatile("s_waitcnt vmcnt(3)" ::: "memory");  // kk's 3 loads landed
    __builtin_amdgcn_s_barrier();
    __builtin_amdgcn_sched_barrier(0);
    COMPUTE(b);
    __builtin_amdgcn_sched_barrier(0);
    __builtin_amdgcn_s_barrier();                     // all reads of buf b done
    __builtin_amdgcn_sched_barrier(0);
  }
  asm volatile("s_waitcnt vmcnt(0)" ::: "memory");
  __builtin_amdgcn_s_barrier();
  __builtin_amdgcn_sched_barrier(0);
  COMPUTE(1);                                         // kk = 15

  // ---- epilogue ----
  if constexpr (MODE == 3) {
    // element: (dout = m-row, xtrow = n-col). store vt[nn][dout][kperm(t)]
    #pragma unroll
    for (int j = 0; j < 4; ++j) {
      int xbase = n0 + wn + j * 16;            // multiple of 16
      int nn    = xbase / 384;
      int bloc  = xbase - nn * 384;
      int off64 = (bloc >> 6) * 64 + ((bloc >> 4) & 3);   // + l15*4 gives k'
      #pragma unroll
      for (int i = 0; i < 4; ++i)
        #pragma unroll
        for (int r = 0; r < 4; ++r) {
          int dout = (int)m0 + wm + i * 16 + quad * 4 + r;
          C[((size_t)nn * 512 + dout) * 384 + off64 + l15 * 4] = f2bf(acc[i][j][r]);
        }
    }
  } else {
    OutT* Cb = C;
    int ncol0 = n0 + wn;
    if constexpr (MODE == 2) {
      int sec = n0 >> 9;                        // 0=q, 1=k
      Cb = C + (size_t)sec * NROWS * 512;
      ncol0 = (n0 & 511) + wn;
    }
    #pragma unroll
    for (int i = 0; i < 4; ++i) {
      #pragma unroll
      for (int r = 0; r < 4; ++r) {
        size_t grow = m0 + wm + i * 16 + quad * 4 + r;
        int t = (int)(grow % 384);
        #pragma unroll
        for (int j = 0; j < 4; ++j) {
          float v = acc[i][j][r];
          int col = ncol0 + j * 16 + l15;
          if constexpr (MODE == 2) {
            if (((ncol0 + j * 16) & 63) < 32) {   // rotary half (wave-uniform)
              float part = __shfl_xor(v, 1);
              float2 scv = tab[t * 16 + ((col & 63) >> 1)];
              v = (l15 & 1) ? (part * scv.x + v * scv.y)
                            : (v * scv.y - part * scv.x);
            }
            Cb[grow * 512 + col] = f2bf(v);
          } else {
            Cb[grow * 512 + col] = v;   // fp32
          }
        }
      }
    }
  }
}

// ------------------------------------------------------------------
// Flash attention. Q/K pre-RoPE'd; V pre-transposed AND k-permuted
// (vt[n][d][k'], k' = (t&15)*4 + (t>>4) within each 64-tile).
// Fixed-max exp2 softmax (no online max), deferred lsum reduction.
// XCD-swizzled so all qt-blocks of one (h,n) share an XCD's L2.
// Invalid neurons (pad==0): y = residual, no attention compute.
// ------------------------------------------------------------------
__global__ __launch_bounds__(256, 4) void attn_kernel(
    const unsigned short* __restrict__ qb,   // [n][t][512]
    const unsigned short* __restrict__ kb,   // [n][t][512]
    const unsigned short* __restrict__ vt,   // [n][512][384] (k-permuted)
    const unsigned short* __restrict__ xt,   // residual [n][t][512]
    const int* __restrict__ pad,             // [128]
    unsigned short* __restrict__ y)          // [t][n][512]
{
  // grid = (6, 8, 128) -> 6144 blocks; chunk = 768 (divisible by 6 and 48)
  const int lin = (int)blockIdx.x + 6 * ((int)blockIdx.y + 8 * (int)blockIdx.z);
  const int swz = (lin & 7) * 768 + (lin >> 3);
  const int qt  = swz % 6;          // 0..5
  const int rem = swz / 6;
  const int h   = rem & 7;          // 0..7
  const int n   = rem >> 3;         // 0..127

  const int tid  = threadIdx.x;

  if (pad[n] == 0) {
    // y = residual only (bf16 copy is exact). 64 rows x 64 cols per block.
    int tq = qt * 64 + (tid >> 2);
    int d  = h * 64 + (tid & 3) * 16;
    const uint4* src = reinterpret_cast<const uint4*>(
        &xt[((size_t)n * T_SEQ + tq) * 512 + d]);
    uint4* dst = reinterpret_cast<uint4*>(
        &y[((size_t)tq * NNEUR + n) * 512 + d]);
    dst[0] = src[0];
    dst[1] = src[1];
    return;
  }

  __shared__ alignas(16) unsigned short Qs[64 * 64];
  __shared__ alignas(16) unsigned short Ks[64 * 64];
  __shared__ alignas(16) unsigned short VTs[64 * 64];
  __shared__ alignas(16) unsigned short Ps[4][16][72];

  const int wave = tid >> 6, lane = tid & 63;
  const int l15  = lane & 15, quad = lane >> 4;
  const int lrow = lane >> 3, lchunk = (lane & 7) ^ ((lane >> 3) & 7);
  const float C2 = 0.18033688011112042f;     // 0.125 * log2(e)

  const unsigned short* gq =
      qb + ((size_t)n * T_SEQ + qt * 64 + wave * 16 + lrow) * 512 + h * 64 + lchunk * 8;
  async_copy16(gq,           &Qs[(wave * 16) * 64]);
  async_copy16(gq + 8 * 512, &Qs[(wave * 16 + 8) * 64]);

  const unsigned short* gk0 =
      kb + ((size_t)n * T_SEQ + wave * 16 + lrow) * 512 + h * 64 + lchunk * 8;
  const unsigned short* gv0 =
      vt + ((size_t)n * 512 + h * 64 + wave * 16 + lrow) * 384 + lchunk * 8;

  float lsum[4] = {0.f, 0.f, 0.f, 0.f};
  f32x4 oacc[4] = {};

  for (int kt = 0; kt <= qt; ++kt) {
    async_copy16(gk0 + (size_t)(kt * 64) * 512,     &Ks[(wave * 16) * 64]);
    async_copy16(gk0 + (size_t)(kt * 64 + 8) * 512, &Ks[(wave * 16 + 8) * 64]);
    async_copy16(gv0 + kt * 64,                     &VTs[(wave * 16) * 64]);
    async_copy16(gv0 + kt * 64 + 8 * 384,           &VTs[(wave * 16 + 8) * 64]);
    __syncthreads();

    // ---- S = Q K^T ----
    f32x4 sc4[4] = {};
    #pragma unroll
    for (int kc = 0; kc < 2; ++kc) {
      const int pc = ((kc * 4 + quad) ^ (l15 & 7)) * 8;
      bf16x8 aq = *reinterpret_cast<const bf16x8*>(&Qs[(wave * 16 + l15) * 64 + pc]);
      #pragma unroll
      for (int tc = 0; tc < 4; ++tc) {
        bf16x8 bk = *reinterpret_cast<const bf16x8*>(&Ks[(tc * 16 + l15) * 64 + pc]);
        sc4[tc] = __builtin_amdgcn_mfma_f32_16x16x32_bf16(aq, bk, sc4[tc], 0, 0, 0);
      }
    }
    // ---- fixed-max exp2 softmax ----
    const bool diag = (kt == qt);
    float ps[4][4];
    #pragma unroll
    for (int tc = 0; tc < 4; ++tc)
      #pragma unroll
      for (int r = 0; r < 4; ++r) {
        float p = fast_exp2(sc4[tc][r] * C2 - 16.0f);
        if (diag && (tc * 16 + l15 > wave * 16 + quad * 4 + r)) p = 0.f;
        lsum[r] += p;
        ps[tc][r] = p;
      }
    // ---- pack P (trunc->bf16) into k'-permuted LDS: k' = l15*4 + tc ----
    #pragma unroll
    for (int r = 0; r < 4; ++r) {
      union { float f; unsigned int u; } a0, a1, a2, a3;
      a0.f = ps[0][r]; a1.f = ps[1][r]; a2.f = ps[2][r]; a3.f = ps[3][r];
      uint2 pk;
      pk.x = (a1.u & 0xffff0000u) | (a0.u >> 16);
      pk.y = (a3.u & 0xffff0000u) | (a2.u >> 16);
      *reinterpret_cast<uint2*>(&Ps[wave][quad * 4 + r][l15 * 4]) = pk;
    }
    // ---- O += P V (both sides k'-permuted) ----
    #pragma unroll
    for (int kc = 0; kc < 2; ++kc) {
      const int pc = ((kc * 4 + quad) ^ (l15 & 7)) * 8;
      bf16x8 ap = *reinterpret_cast<const bf16x8*>(&Ps[wave][l15][kc * 32 + quad * 8]);
      #pragma unroll
      for (int dt = 0; dt < 4; ++dt) {
        bf16x8 bv = *reinterpret_cast<const bf16x8*>(&VTs[(dt * 16 + l15) * 64 + pc]);
        oacc[dt] = __builtin_amdgcn_mfma_f32_16x16x32_bf16(ap, bv, oacc[dt], 0, 0, 0);
      }
    }
    __syncthreads();
  }

  // ---- lsum reduce + epilogue: residual add, write y[t][n][d] ----
  float inv[4];
  #pragma unroll
  for (int r = 0; r < 4; ++r) {
    float l = lsum[r];
    l += __shfl_xor(l, 1);
    l += __shfl_xor(l, 2);
    l += __shfl_xor(l, 4);
    l += __shfl_xor(l, 8);
    inv[r] = 1.0f / l;
  }
  #pragma unroll
  for (int dt = 0; dt < 4; ++dt)
    #pragma unroll
    for (int r = 0; r < 4; ++r) {
      int tq = qt * 64 + wave * 16 + quad * 4 + r;
      int d  = h * 64 + dt * 16 + l15;
      float val = oacc[dt][r] * inv[r];
      float res = bf2f(xt[((size_t)n * T_SEQ + tq) * 512 + d]);
      y[((size_t)tq * NNEUR + n) * 512 + d] = f2bf(val + res);
    }
}

// ------------------------------------------------------------------
extern "C" void kernel_launch(void* const* d_in, const int* in_sizes, int n_in,
                              void* d_out, int out_size, void* d_ws, size_t ws_size,
                              hipStream_t stream) {
  const float* x   = (const float*)d_in[0];
  const int*   pad = (const int*)d_in[1];
  const float* nw  = (const float*)d_in[2];
  const float* wq  = (const float*)d_in[3];
  const float* wk  = (const float*)d_in[4];
  const float* wv  = (const float*)d_in[5];
  const float* wo  = (const float*)d_in[6];
  float* out = (float*)d_out;

  char* ws = (char*)d_ws;
  size_t off = 0;
  auto alloc = [&](size_t bytes) { void* p = ws + off; off += (bytes + 255) & ~(size_t)255; return p; };
  const size_t WELEM  = (size_t)512 * 512;        // elements per weight
  const size_t MBYTES = (size_t)NROWS * 512 * 2;
  unsigned short* wqkv_bf = (unsigned short*)alloc(WELEM * 3 * 2);
  unsigned short* wo_bf   = (unsigned short*)alloc(WELEM * 2);
  float2*         rtab    = (float2*)alloc(384 * 16 * sizeof(float2));
  unsigned short* xt_bf   = (unsigned short*)alloc(MBYTES);
  unsigned short* qk_buf  = (unsigned short*)alloc(MBYTES * 2);
  unsigned short* vt_buf  = (unsigned short*)alloc(MBYTES);
  unsigned short* y_buf   = (unsigned short*)alloc(MBYTES);

  cvt_w_kernel<<<dim3(256, 4), 256, 0, stream>>>(
      wq, wk, wv, wo,
      wqkv_bf, wqkv_bf + WELEM, wqkv_bf + 2 * WELEM, wo_bf);
  rope_tab_kernel<<<24, 256, 0, stream>>>(rtab);
  rmsnorm_kernel<<<NROWS / 4, 256, 0, stream>>>(x, nw, xt_bf);
  // fused Q|K GEMM (+RoPE): grid x = column block (8 -> n0 in [0,1024))
  gemm_k<2, unsigned short><<<dim3(8, NROWS / 256), 512, 0, stream>>>(
      xt_bf, wqkv_bf, qk_buf, rtab, pad);
  // V^T (k-permuted): A = wv (512 rows), B = xt
  gemm_k<3, unsigned short><<<dim3(2, NROWS / 128), 512, 0, stream>>>(
      wqkv_bf + 2 * WELEM, xt_bf, vt_buf, nullptr, pad);
  attn_kernel<<<dim3(6, 8, 128), 256, 0, stream>>>(
      qk_buf, qk_buf + (size_t)NROWS * 512, vt_buf, xt_bf, pad, y_buf);
  // out = y Wo^T (fp32)
  gemm_k<0, float><<<dim3(4, NROWS / 256), 512, 0, stream>>>(
      y_buf, wo_bf, out, nullptr, pad);
}

// Round 4
// 347.942 us; speedup vs baseline: 1.2393x; 1.0138x over previous
//
#include <hip/hip_runtime.h>
#include <hip/hip_bf16.h>
#include <stdint.h>

typedef __bf16 bf16x8 __attribute__((ext_vector_type(8)));
typedef float f32x4 __attribute__((ext_vector_type(4)));

static constexpr int T_SEQ  = 384;
static constexpr int NNEUR  = 128;
static constexpr int DMODEL = 512;
static constexpr int NROWS  = NNEUR * T_SEQ;   // 49152
static constexpr float ROPE_C = 0.8304820237218406f;  // log2(10000)/16

__device__ __forceinline__ float bf2f(unsigned short u) {
  union { unsigned int i; float f; } x; x.i = ((unsigned int)u) << 16; return x.f;
}
__device__ __forceinline__ unsigned short f2bf(float f) {
  union { float f; unsigned int i; } x; x.f = f;
  unsigned int i = x.i;
  i += 0x7FFFu + ((i >> 16) & 1u);   // RNE
  return (unsigned short)(i >> 16);
}
__device__ __forceinline__ float fast_exp2(float x) {
#if __has_builtin(__builtin_amdgcn_exp2f)
  return __builtin_amdgcn_exp2f(x);
#else
  return exp2f(x);
#endif
}

// async global->LDS, 16B per lane; LDS dest = wave-uniform base + lane*16
__device__ __forceinline__ void async_copy16(const unsigned short* g, unsigned short* l) {
  auto gp = reinterpret_cast<const __attribute__((address_space(1))) unsigned int*>(
      reinterpret_cast<uintptr_t>(g));
  auto lp = reinterpret_cast<__attribute__((address_space(3))) unsigned int*>(
      reinterpret_cast<uintptr_t>(l));
  __builtin_amdgcn_global_load_lds(gp, lp, 16, 0, 0);
}

// ------------------------------------------------------------------
// weights fp32 -> bf16
// ------------------------------------------------------------------
__global__ __launch_bounds__(256) void cvt_w_kernel(
    const float* __restrict__ w0, const float* __restrict__ w1,
    const float* __restrict__ w2, const float* __restrict__ w3,
    unsigned short* __restrict__ o0, unsigned short* __restrict__ o1,
    unsigned short* __restrict__ o2, unsigned short* __restrict__ o3)
{
  const float* w; unsigned short* o;
  switch (blockIdx.y) {
    case 0:  w = w0; o = o0; break;
    case 1:  w = w1; o = o1; break;
    case 2:  w = w2; o = o2; break;
    default: w = w3; o = o3; break;
  }
  int i = (blockIdx.x * 256 + threadIdx.x) * 4;
  float4 v = *reinterpret_cast<const float4*>(w + i);
  union { unsigned short u[4]; uint2 v2; } p;
  p.u[0] = f2bf(v.x); p.u[1] = f2bf(v.y); p.u[2] = f2bf(v.z); p.u[3] = f2bf(v.w);
  *reinterpret_cast<uint2*>(o + i) = p.v2;
}

// rope table: tab[t*16+i] = (sin, cos) of t * 10000^(-i/16)
__global__ __launch_bounds__(256) void rope_tab_kernel(float2* __restrict__ tab) {
  int idx = blockIdx.x * 256 + threadIdx.x;   // 6144
  int t = idx >> 4, i = idx & 15;
  float ang = (float)t * exp2f(-(float)i * ROPE_C);
  float s, c; sincosf(ang, &s, &c);
  tab[idx] = make_float2(s, c);
}

// ------------------------------------------------------------------
// RMSNorm: x[t][n][d] fp32 -> xt_bf[n][t][d] bf16 (also the residual)
// ------------------------------------------------------------------
__global__ __launch_bounds__(256) void rmsnorm_kernel(
    const float* __restrict__ x, const float* __restrict__ nw,
    unsigned short* __restrict__ xt)
{
  int wave = threadIdx.x >> 6, lane = threadIdx.x & 63;
  int rid = blockIdx.x * 4 + wave;       // rid = t*128 + n
  int t = rid >> 7, n = rid & 127;
  const float* row = x + (size_t)rid * DMODEL;
  float4 v0 = *reinterpret_cast<const float4*>(row + lane * 8);
  float4 v1 = *reinterpret_cast<const float4*>(row + lane * 8 + 4);
  float ss = v0.x*v0.x + v0.y*v0.y + v0.z*v0.z + v0.w*v0.w
           + v1.x*v1.x + v1.y*v1.y + v1.z*v1.z + v1.w*v1.w;
  #pragma unroll
  for (int off = 32; off; off >>= 1) ss += __shfl_xor(ss, off);
  float sc = rsqrtf(ss * (1.0f / DMODEL) + 1e-6f);
  float4 w0 = *reinterpret_cast<const float4*>(nw + lane * 8);
  float4 w1 = *reinterpret_cast<const float4*>(nw + lane * 8 + 4);
  union { unsigned short u[8]; uint4 v; } p;
  p.u[0] = f2bf(v0.x * sc * w0.x); p.u[1] = f2bf(v0.y * sc * w0.y);
  p.u[2] = f2bf(v0.z * sc * w0.z); p.u[3] = f2bf(v0.w * sc * w0.w);
  p.u[4] = f2bf(v1.x * sc * w1.x); p.u[5] = f2bf(v1.y * sc * w1.y);
  p.u[6] = f2bf(v1.z * sc * w1.z); p.u[7] = f2bf(v1.w * sc * w1.w);
  *reinterpret_cast<uint4*>(xt + ((size_t)n * T_SEQ + t) * DMODEL + lane * 8) = p.v;
}

// ------------------------------------------------------------------
// GEMM: D[m][n] = sum_k A[m][k]*B[n][k], bf16 in, fp32 acc.
// 256x128 tile, 512 threads / 8 waves (4m x 2n), 16x16x32 MFMA.
// BK=32 double-buffered 2-phase pipeline with raw s_barrier + counted
// vmcnt(3). XCD-aware chunked block swizzle. Pad-mask dead-tile skip.
// MODE 0: fp32 row-major store (out = y Wo^T)
// MODE 2: bf16 row-major store + table RoPE; C covers q|k sections (n0>>9)
// MODE 3: bf16 transposed + k-permuted store -> vt[nn][dout][kperm(t)]
// ------------------------------------------------------------------
template <int MODE, typename OutT>
__global__ __launch_bounds__(512, 4) void gemm_k(
    const unsigned short* __restrict__ A,
    const unsigned short* __restrict__ B,
    OutT* __restrict__ C,
    const float2* __restrict__ tab,
    const int* __restrict__ pad)
{
  // per buffer: A 256x32 (8192) + B 128x32 (4096) = 12288 elems; x2 = 48 KiB
  __shared__ alignas(16) unsigned short Sh[2][12288];
  const int tid  = threadIdx.x;
  const int wave = tid >> 6, lane = tid & 63;
  const int l15  = lane & 15, quad = lane >> 4;
  const int wm = (wave >> 1) * 64, wn = (wave & 1) * 64;

  // XCD-aware chunked swizzle (bijective: NB % 8 == 0, chunk % GX == 0)
  constexpr int GX = (MODE == 2) ? 8 : (MODE == 3) ? 2 : 4;
  constexpr int GY = (MODE == 3) ? 384 : 192;
  constexpr int NB = GX * GY;
  constexpr int CH = NB / 8;
  const int lin = (int)blockIdx.y * GX + (int)blockIdx.x;
  const int swz = (lin & 7) * CH + (lin >> 3);
  const int bx  = swz % GX, by = swz / GX;

  size_t m0; int n0;
  if constexpr (MODE == 3) { m0 = (size_t)bx * 256; n0 = by * 128; }
  else                     { m0 = (size_t)by * 256; n0 = bx * 128; }

  // dead-tile skip (wave-uniform) -- BEFORE any staging is issued
  if constexpr (MODE == 2) {
    int nfirst = (int)(m0 / 384);
    int nlast  = (int)((m0 + 255) / 384);
    if (pad[nfirst] == 0 && pad[nlast] == 0) return;
  }
  if constexpr (MODE == 3) {
    if (pad[n0 / 384] == 0) return;   // 128-col tile lies in one neuron
  }

  // staging geometry: thread covers row r4 (+128 for 2nd A copy), chunk c4
  const int r4 = tid >> 2;                 // 0..127
  const int c4 = tid & 3;
  const int gc = c4 ^ (r4 & 3);            // swizzled global chunk
  const unsigned short* ga = A + (m0 + r4) * 512 + gc * 8;
  const unsigned short* gb = B + ((size_t)n0 + r4) * 512 + gc * 8;

  // LDS->reg fragment chunk (unswizzle): row = ..+l15 so row&3 == l15&3
  const int pc = (quad ^ (l15 & 3)) * 8;

  auto STAGE = [&](int kk, int b) {
    const unsigned short* gak = ga + kk * 32;
    unsigned short* base = &Sh[b][0];
    async_copy16(gak,             base + tid * 8);          // A rows 0-127
    async_copy16(gak + 128 * 512, base + 4096 + tid * 8);   // A rows 128-255
    async_copy16(gb + kk * 32,    base + 8192 + tid * 8);   // B rows 0-127
  };

  f32x4 acc[4][4] = {};
  auto COMPUTE = [&](int b) {
    const unsigned short* base = &Sh[b][0];
    bf16x8 a[4], bb[4];
    #pragma unroll
    for (int i = 0; i < 4; ++i)
      a[i] = *reinterpret_cast<const bf16x8*>(&base[(wm + i * 16 + l15) * 32 + pc]);
    #pragma unroll
    for (int j = 0; j < 4; ++j)
      bb[j] = *reinterpret_cast<const bf16x8*>(&base[8192 + (wn + j * 16 + l15) * 32 + pc]);
    #pragma unroll
    for (int i = 0; i < 4; ++i)
      #pragma unroll
      for (int j = 0; j < 4; ++j)
        acc[i][j] = __builtin_amdgcn_mfma_f32_16x16x32_bf16(a[i], bb[j], acc[i][j], 0, 0, 0);
  };

  STAGE(0, 0);
  #pragma unroll 2
  for (int kk = 0; kk < 15; ++kk) {
    const int b = kk & 1;
    STAGE(kk + 1, b ^ 1);
    asm volatile("s_waitcnt vmcnt(3)" ::: "memory");  // kk's 3 loads landed
    __builtin_amdgcn_s_barrier();
    __builtin_amdgcn_sched_barrier(0);
    COMPUTE(b);
    __builtin_amdgcn_sched_barrier(0);
    __builtin_amdgcn_s_barrier();                     // all reads of buf b done
    __builtin_amdgcn_sched_barrier(0);
  }
  asm volatile("s_waitcnt vmcnt(0)" ::: "memory");
  __builtin_amdgcn_s_barrier();
  __builtin_amdgcn_sched_barrier(0);
  COMPUTE(1);                                         // kk = 15

  // ---- epilogue ----
  if constexpr (MODE == 3) {
    // element: (dout = m-row, xtrow = n-col). store vt[nn][dout][kperm(t)]
    #pragma unroll
    for (int j = 0; j < 4; ++j) {
      int xbase = n0 + wn + j * 16;            // multiple of 16
      int nn    = xbase / 384;
      int bloc  = xbase - nn * 384;
      int off64 = (bloc >> 6) * 64 + ((bloc >> 4) & 3);   // + l15*4 gives k'
      #pragma unroll
      for (int i = 0; i < 4; ++i)
        #pragma unroll
        for (int r = 0; r < 4; ++r) {
          int dout = (int)m0 + wm + i * 16 + quad * 4 + r;
          C[((size_t)nn * 512 + dout) * 384 + off64 + l15 * 4] = f2bf(acc[i][j][r]);
        }
    }
  } else {
    OutT* Cb = C;
    int ncol0 = n0 + wn;
    if constexpr (MODE == 2) {
      int sec = n0 >> 9;                        // 0=q, 1=k
      Cb = C + (size_t)sec * NROWS * 512;
      ncol0 = (n0 & 511) + wn;
    }
    #pragma unroll
    for (int i = 0; i < 4; ++i) {
      #pragma unroll
      for (int r = 0; r < 4; ++r) {
        size_t grow = m0 + wm + i * 16 + quad * 4 + r;
        int t = (int)(grow % 384);
        #pragma unroll
        for (int j = 0; j < 4; ++j) {
          float v = acc[i][j][r];
          int col = ncol0 + j * 16 + l15;
          if constexpr (MODE == 2) {
            if (((ncol0 + j * 16) & 63) < 32) {   // rotary half (wave-uniform)
              float part = __shfl_xor(v, 1);
              float2 scv = tab[t * 16 + ((col & 63) >> 1)];
              v = (l15 & 1) ? (part * scv.x + v * scv.y)
                            : (v * scv.y - part * scv.x);
            }
            Cb[grow * 512 + col] = f2bf(v);
          } else {
            Cb[grow * 512 + col] = v;   // fp32
          }
        }
      }
    }
  }
}

// ------------------------------------------------------------------
// Flash attention, QBLK=128. Q/K pre-RoPE'd; V pre-transposed AND
// k-permuted (vt[n][d][k'], k' = (t&15)*4 + (t>>4) within each 64-tile).
// Each block: 128 q-rows (4 waves x 32 rows = 2 sub-tiles of 16).
// Q fragments hoisted to registers (loop-invariant).
// K/V 64-tiles staged per iteration; half the staging+barriers per MFMA
// vs QBLK=64. Fixed-max exp2 softmax; always-on causal compare (two
// k-tiles straddle the diagonal now); wave-uniform skip of fully-masked
// sub-tiles. Invalid neurons (pad==0): y = residual copy.
// ------------------------------------------------------------------
__global__ __launch_bounds__(256, 4) void attn_kernel(
    const unsigned short* __restrict__ qb,   // [n][t][512]
    const unsigned short* __restrict__ kb,   // [n][t][512]
    const unsigned short* __restrict__ vt,   // [n][512][384] (k-permuted)
    const unsigned short* __restrict__ xt,   // residual [n][t][512]
    const int* __restrict__ pad,             // [128]
    unsigned short* __restrict__ y)          // [t][n][512]
{
  // grid = (3, 8, 128) -> 3072 blocks; chunk = 384 (divisible by 3)
  const int lin = (int)blockIdx.x + 3 * ((int)blockIdx.y + 8 * (int)blockIdx.z);
  const int swz = (lin & 7) * 384 + (lin >> 3);
  const int qtb = swz % 3;          // 0..2 (128 q-rows each)
  const int rem = swz / 3;
  const int h   = rem & 7;          // 0..7
  const int n   = rem >> 3;         // 0..127

  const int tid  = threadIdx.x;

  if (pad[n] == 0) {
    // y = residual only (bf16 copy is exact). 128 rows x 64 cols.
    int rb = tid >> 2;
    int d  = h * 64 + (tid & 3) * 16;
    #pragma unroll
    for (int rr = 0; rr < 128; rr += 64) {
      int tq = qtb * 128 + rr + rb;
      const uint4* src = reinterpret_cast<const uint4*>(
          &xt[((size_t)n * T_SEQ + tq) * 512 + d]);
      uint4* dst = reinterpret_cast<uint4*>(
          &y[((size_t)tq * NNEUR + n) * 512 + d]);
      dst[0] = src[0];
      dst[1] = src[1];
    }
    return;
  }

  __shared__ alignas(16) unsigned short Qs[128 * 64];
  __shared__ alignas(16) unsigned short Ks[64 * 64];
  __shared__ alignas(16) unsigned short VTs[64 * 64];
  __shared__ alignas(16) unsigned short Ps[4][16][72];

  const int wave = tid >> 6, lane = tid & 63;
  const int l15  = lane & 15, quad = lane >> 4;
  const int lrow = lane >> 3, lchunk = (lane & 7) ^ ((lane >> 3) & 7);
  const float C2 = 0.18033688011112042f;     // 0.125 * log2(e)

  // stage Q (128x64, 4 copies of 8 rows per wave)
  const unsigned short* gq =
      qb + ((size_t)n * T_SEQ + qtb * 128 + wave * 32 + lrow) * 512 + h * 64 + lchunk * 8;
  #pragma unroll
  for (int rr = 0; rr < 4; ++rr)
    async_copy16(gq + (size_t)(rr * 8) * 512, &Qs[(wave * 32 + rr * 8) * 64]);

  const unsigned short* gk0 =
      kb + ((size_t)n * T_SEQ + wave * 16 + lrow) * 512 + h * 64 + lchunk * 8;
  const unsigned short* gv0 =
      vt + ((size_t)n * 512 + h * 64 + wave * 16 + lrow) * 384 + lchunk * 8;

  const int nkt = 2 * qtb + 2;

  float lsum[2][4] = {};
  f32x4 oacc[2][4] = {};

  // stage K/V tile 0
  async_copy16(gk0,           &Ks[(wave * 16) * 64]);
  async_copy16(gk0 + 8 * 512, &Ks[(wave * 16 + 8) * 64]);
  async_copy16(gv0,           &VTs[(wave * 16) * 64]);
  async_copy16(gv0 + 8 * 384, &VTs[(wave * 16 + 8) * 64]);
  __syncthreads();

  // Q fragments -> registers (loop-invariant across kt)
  bf16x8 aq[2][2];
  #pragma unroll
  for (int s = 0; s < 2; ++s)
    #pragma unroll
    for (int kc = 0; kc < 2; ++kc) {
      const int pcq = ((kc * 4 + quad) ^ (l15 & 7)) * 8;
      aq[s][kc] = *reinterpret_cast<const bf16x8*>(
          &Qs[(wave * 32 + s * 16 + l15) * 64 + pcq]);
    }

  for (int kt = 0; kt < nkt; ++kt) {
    #pragma unroll
    for (int s = 0; s < 2; ++s) {
      const int qsub = qtb * 128 + wave * 32 + s * 16;   // first q-row of sub
      if (kt * 64 > qsub + 15) continue;                 // fully masked (uniform)

      // ---- S = Q K^T ----
      f32x4 sc4[4] = {};
      #pragma unroll
      for (int kc = 0; kc < 2; ++kc) {
        const int pc = ((kc * 4 + quad) ^ (l15 & 7)) * 8;
        #pragma unroll
        for (int tc = 0; tc < 4; ++tc) {
          bf16x8 bk = *reinterpret_cast<const bf16x8*>(&Ks[(tc * 16 + l15) * 64 + pc]);
          sc4[tc] = __builtin_amdgcn_mfma_f32_16x16x32_bf16(aq[s][kc], bk, sc4[tc], 0, 0, 0);
        }
      }
      // ---- fixed-max exp2 softmax + causal mask ----
      float ps_[4][4];
      #pragma unroll
      for (int tc = 0; tc < 4; ++tc)
        #pragma unroll
        for (int r = 0; r < 4; ++r) {
          float p = fast_exp2(sc4[tc][r] * C2 - 16.0f);
          int kglob = kt * 64 + tc * 16 + l15;
          int qglob = qsub + quad * 4 + r;
          if (kglob > qglob) p = 0.f;
          lsum[s][r] += p;
          ps_[tc][r] = p;
        }
      // ---- pack P (trunc->bf16) into k'-permuted LDS: k' = l15*4 + tc ----
      #pragma unroll
      for (int r = 0; r < 4; ++r) {
        union { float f; unsigned int u; } a0, a1, a2, a3;
        a0.f = ps_[0][r]; a1.f = ps_[1][r]; a2.f = ps_[2][r]; a3.f = ps_[3][r];
        uint2 pk;
        pk.x = (a1.u & 0xffff0000u) | (a0.u >> 16);
        pk.y = (a3.u & 0xffff0000u) | (a2.u >> 16);
        *reinterpret_cast<uint2*>(&Ps[wave][quad * 4 + r][l15 * 4]) = pk;
      }
      // ---- O += P V (both sides k'-permuted) ----
      #pragma unroll
      for (int kc = 0; kc < 2; ++kc) {
        const int pc = ((kc * 4 + quad) ^ (l15 & 7)) * 8;
        bf16x8 ap = *reinterpret_cast<const bf16x8*>(&Ps[wave][l15][kc * 32 + quad * 8]);
        #pragma unroll
        for (int dt = 0; dt < 4; ++dt) {
          bf16x8 bv = *reinterpret_cast<const bf16x8*>(&VTs[(dt * 16 + l15) * 64 + pc]);
          oacc[s][dt] = __builtin_amdgcn_mfma_f32_16x16x32_bf16(ap, bv, oacc[s][dt], 0, 0, 0);
        }
      }
    }
    if (kt + 1 < nkt) {
      __syncthreads();   // all waves done reading Ks/VTs
      const size_t ko = (size_t)(kt + 1) * 64;
      async_copy16(gk0 + ko * 512,                 &Ks[(wave * 16) * 64]);
      async_copy16(gk0 + (ko + 8) * 512,           &Ks[(wave * 16 + 8) * 64]);
      async_copy16(gv0 + (kt + 1) * 64,            &VTs[(wave * 16) * 64]);
      async_copy16(gv0 + (kt + 1) * 64 + 8 * 384,  &VTs[(wave * 16 + 8) * 64]);
      __syncthreads();   // staged (vmcnt drained by compiler before barrier)
    }
  }

  // ---- lsum reduce + epilogue: residual add, write y[t][n][d] ----
  float inv[2][4];
  #pragma unroll
  for (int s = 0; s < 2; ++s)
    #pragma unroll
    for (int r = 0; r < 4; ++r) {
      float l = lsum[s][r];
      l += __shfl_xor(l, 1);
      l += __shfl_xor(l, 2);
      l += __shfl_xor(l, 4);
      l += __shfl_xor(l, 8);
      inv[s][r] = 1.0f / l;
    }
  #pragma unroll
  for (int s = 0; s < 2; ++s)
    #pragma unroll
    for (int dt = 0; dt < 4; ++dt)
      #pragma unroll
      for (int r = 0; r < 4; ++r) {
        int tq = qtb * 128 + wave * 32 + s * 16 + quad * 4 + r;
        int d  = h * 64 + dt * 16 + l15;
        float val = oacc[s][dt][r] * inv[s][r];
        float res = bf2f(xt[((size_t)n * T_SEQ + tq) * 512 + d]);
        y[((size_t)tq * NNEUR + n) * 512 + d] = f2bf(val + res);
      }
}

// ------------------------------------------------------------------
extern "C" void kernel_launch(void* const* d_in, const int* in_sizes, int n_in,
                              void* d_out, int out_size, void* d_ws, size_t ws_size,
                              hipStream_t stream) {
  const float* x   = (const float*)d_in[0];
  const int*   pad = (const int*)d_in[1];
  const float* nw  = (const float*)d_in[2];
  const float* wq  = (const float*)d_in[3];
  const float* wk  = (const float*)d_in[4];
  const float* wv  = (const float*)d_in[5];
  const float* wo  = (const float*)d_in[6];
  float* out = (float*)d_out;

  char* ws = (char*)d_ws;
  size_t off = 0;
  auto alloc = [&](size_t bytes) { void* p = ws + off; off += (bytes + 255) & ~(size_t)255; return p; };
  const size_t WELEM  = (size_t)512 * 512;        // elements per weight
  const size_t MBYTES = (size_t)NROWS * 512 * 2;
  unsigned short* wqkv_bf = (unsigned short*)alloc(WELEM * 3 * 2);
  unsigned short* wo_bf   = (unsigned short*)alloc(WELEM * 2);
  float2*         rtab    = (float2*)alloc(384 * 16 * sizeof(float2));
  unsigned short* xt_bf   = (unsigned short*)alloc(MBYTES);
  unsigned short* qk_buf  = (unsigned short*)alloc(MBYTES * 2);
  unsigned short* vt_buf  = (unsigned short*)alloc(MBYTES);
  unsigned short* y_buf   = (unsigned short*)alloc(MBYTES);

  cvt_w_kernel<<<dim3(256, 4), 256, 0, stream>>>(
      wq, wk, wv, wo,
      wqkv_bf, wqkv_bf + WELEM, wqkv_bf + 2 * WELEM, wo_bf);
  rope_tab_kernel<<<24, 256, 0, stream>>>(rtab);
  rmsnorm_kernel<<<NROWS / 4, 256, 0, stream>>>(x, nw, xt_bf);
  // fused Q|K GEMM (+RoPE): grid x = column block (8 -> n0 in [0,1024))
  gemm_k<2, unsigned short><<<dim3(8, NROWS / 256), 512, 0, stream>>>(
      xt_bf, wqkv_bf, qk_buf, rtab, pad);
  // V^T (k-permuted): A = wv (512 rows), B = xt
  gemm_k<3, unsigned short><<<dim3(2, NROWS / 128), 512, 0, stream>>>(
      wqkv_bf + 2 * WELEM, xt_bf, vt_buf, nullptr, pad);
  attn_kernel<<<dim3(3, 8, 128), 256, 0, stream>>>(
      qk_buf, qk_buf + (size_t)NROWS * 512, vt_buf, xt_bf, pad, y_buf);
  // out = y Wo^T (fp32)
  gemm_k<0, float><<<dim3(4, NROWS / 256), 512, 0, stream>>>(
      y_buf, wo_bf, out, nullptr, pad);
}

// Round 5
// 341.979 us; speedup vs baseline: 1.2609x; 1.0174x over previous
//
#include <hip/hip_runtime.h>
#include <hip/hip_bf16.h>
#include <stdint.h>

typedef __bf16 bf16x8 __attribute__((ext_vector_type(8)));
typedef float f32x4 __attribute__((ext_vector_type(4)));

static constexpr int T_SEQ  = 384;
static constexpr int NNEUR  = 128;
static constexpr int DMODEL = 512;
static constexpr int NROWS  = NNEUR * T_SEQ;   // 49152
static constexpr float ROPE_C = 0.8304820237218406f;  // log2(10000)/16

__device__ __forceinline__ float bf2f(unsigned short u) {
  union { unsigned int i; float f; } x; x.i = ((unsigned int)u) << 16; return x.f;
}
__device__ __forceinline__ unsigned short f2bf(float f) {
  union { float f; unsigned int i; } x; x.f = f;
  unsigned int i = x.i;
  i += 0x7FFFu + ((i >> 16) & 1u);   // RNE
  return (unsigned short)(i >> 16);
}
__device__ __forceinline__ float fast_exp2(float x) {
#if __has_builtin(__builtin_amdgcn_exp2f)
  return __builtin_amdgcn_exp2f(x);
#else
  return exp2f(x);
#endif
}

// async global->LDS, 16B per lane; LDS dest = wave-uniform base + lane*16
__device__ __forceinline__ void async_copy16(const unsigned short* g, unsigned short* l) {
  auto gp = reinterpret_cast<const __attribute__((address_space(1))) unsigned int*>(
      reinterpret_cast<uintptr_t>(g));
  auto lp = reinterpret_cast<__attribute__((address_space(3))) unsigned int*>(
      reinterpret_cast<uintptr_t>(l));
  __builtin_amdgcn_global_load_lds(gp, lp, 16, 0, 0);
}

// ------------------------------------------------------------------
// prep: weights fp32 -> bf16 (y=0..3) + rope table (y=4)
// tab[t*16+i] = (sin, cos) of t * 10000^(-i/16)
// ------------------------------------------------------------------
__global__ __launch_bounds__(256) void prep_kernel(
    const float* __restrict__ w0, const float* __restrict__ w1,
    const float* __restrict__ w2, const float* __restrict__ w3,
    unsigned short* __restrict__ o0, unsigned short* __restrict__ o1,
    unsigned short* __restrict__ o2, unsigned short* __restrict__ o3,
    float2* __restrict__ tab)
{
  if (blockIdx.y == 4) {
    if (blockIdx.x >= 24) return;
    int idx = blockIdx.x * 256 + threadIdx.x;   // 6144
    int t = idx >> 4, i = idx & 15;
    float ang = (float)t * exp2f(-(float)i * ROPE_C);
    float s, c; sincosf(ang, &s, &c);
    tab[idx] = make_float2(s, c);
    return;
  }
  const float* w; unsigned short* o;
  switch (blockIdx.y) {
    case 0:  w = w0; o = o0; break;
    case 1:  w = w1; o = o1; break;
    case 2:  w = w2; o = o2; break;
    default: w = w3; o = o3; break;
  }
  int i = (blockIdx.x * 256 + threadIdx.x) * 4;
  float4 v = *reinterpret_cast<const float4*>(w + i);
  union { unsigned short u[4]; uint2 v2; } p;
  p.u[0] = f2bf(v.x); p.u[1] = f2bf(v.y); p.u[2] = f2bf(v.z); p.u[3] = f2bf(v.w);
  *reinterpret_cast<uint2*>(o + i) = p.v2;
}

// ------------------------------------------------------------------
// RMSNorm: x[t][n][d] fp32 -> xt_bf[n][t][d] bf16 (also the residual)
// ------------------------------------------------------------------
__global__ __launch_bounds__(256) void rmsnorm_kernel(
    const float* __restrict__ x, const float* __restrict__ nw,
    unsigned short* __restrict__ xt)
{
  int wave = threadIdx.x >> 6, lane = threadIdx.x & 63;
  int rid = blockIdx.x * 4 + wave;       // rid = t*128 + n
  int t = rid >> 7, n = rid & 127;
  const float* row = x + (size_t)rid * DMODEL;
  float4 v0 = *reinterpret_cast<const float4*>(row + lane * 8);
  float4 v1 = *reinterpret_cast<const float4*>(row + lane * 8 + 4);
  float ss = v0.x*v0.x + v0.y*v0.y + v0.z*v0.z + v0.w*v0.w
           + v1.x*v1.x + v1.y*v1.y + v1.z*v1.z + v1.w*v1.w;
  #pragma unroll
  for (int off = 32; off; off >>= 1) ss += __shfl_xor(ss, off);
  float sc = rsqrtf(ss * (1.0f / DMODEL) + 1e-6f);
  float4 w0 = *reinterpret_cast<const float4*>(nw + lane * 8);
  float4 w1 = *reinterpret_cast<const float4*>(nw + lane * 8 + 4);
  union { unsigned short u[8]; uint4 v; } p;
  p.u[0] = f2bf(v0.x * sc * w0.x); p.u[1] = f2bf(v0.y * sc * w0.y);
  p.u[2] = f2bf(v0.z * sc * w0.z); p.u[3] = f2bf(v0.w * sc * w0.w);
  p.u[4] = f2bf(v1.x * sc * w1.x); p.u[5] = f2bf(v1.y * sc * w1.y);
  p.u[6] = f2bf(v1.z * sc * w1.z); p.u[7] = f2bf(v1.w * sc * w1.w);
  *reinterpret_cast<uint4*>(xt + ((size_t)n * T_SEQ + t) * DMODEL + lane * 8) = p.v;
}

// ------------------------------------------------------------------
// GEMM: D[m][n] = sum_k A[m][k]*B[n][k], bf16 in, fp32 acc.
// m97-proven geometry: 128x128 tile, BK=64, 256 threads / 4 waves
// (2m x 2n, 64x64 per wave), single 32 KiB LDS buffer, plain
// __syncthreads, global_load_lds w16 staging with XOR chunk swizzle.
// 4 blocks/CU. XCD-aware chunked block swizzle for A-panel L2 reuse.
// 384 = 3*128 so every 128-row tile lies in ONE neuron -> exact
// pad-mask skip (attn ignores invalid neurons' q/k/v).
// MODE 0: fp32 row-major store (out = y Wo^T)
// MODE 2: bf16 row-major store + table RoPE; C covers q|k sections (n0>>9)
// MODE 3: bf16 transposed + k-permuted store -> vt[nn][dout][kperm(t)]
// ------------------------------------------------------------------
template <int MODE, typename OutT>
__global__ __launch_bounds__(256, 4) void gemm_k(
    const unsigned short* __restrict__ A,
    const unsigned short* __restrict__ B,
    OutT* __restrict__ C,
    const float2* __restrict__ tab,
    const int* __restrict__ pad)
{
  __shared__ alignas(16) unsigned short Sh[256 * 64];   // rows 0-127 A, 128-255 B
  const int tid  = threadIdx.x;
  const int wave = tid >> 6, lane = tid & 63;
  const int l15  = lane & 15, quad = lane >> 4;
  const int wm = (wave >> 1) * 64, wn = (wave & 1) * 64;

  // XCD-aware chunked swizzle (bijective: NB % 8 == 0, chunk % GX == 0)
  constexpr int GX = (MODE == 2) ? 8 : 4;
  constexpr int GY = 384;
  constexpr int NB = GX * GY;
  constexpr int CH = NB / 8;
  const int lin = (int)blockIdx.y * GX + (int)blockIdx.x;
  const int swz = (lin & 7) * CH + (lin >> 3);
  const int bx  = swz % GX, by = swz / GX;

  size_t m0; int n0;
  if constexpr (MODE == 3) { m0 = (size_t)bx * 128; n0 = by * 128; }
  else                     { m0 = (size_t)by * 128; n0 = bx * 128; }

  // dead-tile skip (wave-uniform); 128-row/col tiles lie in ONE neuron
  if constexpr (MODE == 2) {
    if (pad[(int)(m0 / 384)] == 0) return;
  }
  if constexpr (MODE == 3) {
    if (pad[n0 / 384] == 0) return;
  }

  // staging geometry: base row r0 = tid>>3 (+32 per round), chunk tid&7
  const int r0 = tid >> 3;                 // 0..31
  const int gc = (tid & 7) ^ (r0 & 7);     // swizzled global chunk (row&7 == r0&7)
  const unsigned short* ga = A + (m0 + r0) * 512 + gc * 8;
  const unsigned short* gb = B + ((size_t)n0 + r0) * 512 + gc * 8;
  unsigned short* ls = &Sh[tid * 8];

  f32x4 acc[4][4] = {};
  for (int k0 = 0; k0 < 512; k0 += 64) {
    #pragma unroll
    for (int rr = 0; rr < 4; ++rr) {
      async_copy16(ga + (size_t)rr * 32 * 512 + k0, ls + rr * 2048);          // A
      async_copy16(gb + (size_t)rr * 32 * 512 + k0, ls + 8192 + rr * 2048);   // B
    }
    __syncthreads();
    #pragma unroll
    for (int kc = 0; kc < 2; ++kc) {
      const int pc = ((kc * 4 + quad) ^ (l15 & 7)) * 8;
      bf16x8 a[4], b[4];
      #pragma unroll
      for (int i = 0; i < 4; ++i)
        a[i] = *reinterpret_cast<const bf16x8*>(&Sh[(wm + i * 16 + l15) * 64 + pc]);
      #pragma unroll
      for (int j = 0; j < 4; ++j)
        b[j] = *reinterpret_cast<const bf16x8*>(&Sh[(128 + wn + j * 16 + l15) * 64 + pc]);
      #pragma unroll
      for (int i = 0; i < 4; ++i)
        #pragma unroll
        for (int j = 0; j < 4; ++j)
          acc[i][j] = __builtin_amdgcn_mfma_f32_16x16x32_bf16(a[i], b[j], acc[i][j], 0, 0, 0);
    }
    __syncthreads();
  }

  // ---- epilogue ----
  if constexpr (MODE == 3) {
    // element: (dout = m-row, xtrow = n-col). store vt[nn][dout][kperm(t)]
    #pragma unroll
    for (int j = 0; j < 4; ++j) {
      int xbase = n0 + wn + j * 16;            // multiple of 16
      int nn    = xbase / 384;
      int bloc  = xbase - nn * 384;
      int off64 = (bloc >> 6) * 64 + ((bloc >> 4) & 3);   // + l15*4 gives k'
      #pragma unroll
      for (int i = 0; i < 4; ++i)
        #pragma unroll
        for (int r = 0; r < 4; ++r) {
          int dout = (int)m0 + wm + i * 16 + quad * 4 + r;
          C[((size_t)nn * 512 + dout) * 384 + off64 + l15 * 4] = f2bf(acc[i][j][r]);
        }
    }
  } else {
    OutT* Cb = C;
    int ncol0 = n0 + wn;
    if constexpr (MODE == 2) {
      int sec = n0 >> 9;                        // 0=q, 1=k (tiles don't straddle 512)
      Cb = C + (size_t)sec * NROWS * 512;
      ncol0 = (n0 & 511) + wn;
    }
    #pragma unroll
    for (int i = 0; i < 4; ++i) {
      #pragma unroll
      for (int r = 0; r < 4; ++r) {
        size_t grow = m0 + wm + i * 16 + quad * 4 + r;
        int t = (int)(grow % 384);
        #pragma unroll
        for (int j = 0; j < 4; ++j) {
          float v = acc[i][j][r];
          int col = ncol0 + j * 16 + l15;
          if constexpr (MODE == 2) {
            if (((ncol0 + j * 16) & 63) < 32) {   // rotary half (wave-uniform)
              float part = __shfl_xor(v, 1);
              float2 scv = tab[t * 16 + ((col & 63) >> 1)];
              v = (l15 & 1) ? (part * scv.x + v * scv.y)
                            : (v * scv.y - part * scv.x);
            }
            Cb[grow * 512 + col] = f2bf(v);
          } else {
            Cb[grow * 512 + col] = v;   // fp32
          }
        }
      }
    }
  }
}

// ------------------------------------------------------------------
// Flash attention, QBLK=128. Q/K pre-RoPE'd; V pre-transposed AND
// k-permuted (vt[n][d][k'], k' = (t&15)*4 + (t>>4) within each 64-tile).
// Each block: 128 q-rows (4 waves x 32 rows = 2 sub-tiles of 16).
// Q fragments hoisted to registers (loop-invariant).
// Fixed-max exp2 softmax; always-on causal compare; wave-uniform skip
// of fully-masked sub-tiles. Invalid neurons (pad==0): y = residual.
// ------------------------------------------------------------------
__global__ __launch_bounds__(256, 4) void attn_kernel(
    const unsigned short* __restrict__ qb,   // [n][t][512]
    const unsigned short* __restrict__ kb,   // [n][t][512]
    const unsigned short* __restrict__ vt,   // [n][512][384] (k-permuted)
    const unsigned short* __restrict__ xt,   // residual [n][t][512]
    const int* __restrict__ pad,             // [128]
    unsigned short* __restrict__ y)          // [t][n][512]
{
  // grid = (3, 8, 128) -> 3072 blocks; chunk = 384 (divisible by 3)
  const int lin = (int)blockIdx.x + 3 * ((int)blockIdx.y + 8 * (int)blockIdx.z);
  const int swz = (lin & 7) * 384 + (lin >> 3);
  const int qtb = swz % 3;          // 0..2 (128 q-rows each)
  const int rem = swz / 3;
  const int h   = rem & 7;          // 0..7
  const int n   = rem >> 3;         // 0..127

  const int tid  = threadIdx.x;

  if (pad[n] == 0) {
    // y = residual only (bf16 copy is exact). 128 rows x 64 cols.
    int rb = tid >> 2;
    int d  = h * 64 + (tid & 3) * 16;
    #pragma unroll
    for (int rr = 0; rr < 128; rr += 64) {
      int tq = qtb * 128 + rr + rb;
      const uint4* src = reinterpret_cast<const uint4*>(
          &xt[((size_t)n * T_SEQ + tq) * 512 + d]);
      uint4* dst = reinterpret_cast<uint4*>(
          &y[((size_t)tq * NNEUR + n) * 512 + d]);
      dst[0] = src[0];
      dst[1] = src[1];
    }
    return;
  }

  __shared__ alignas(16) unsigned short Qs[128 * 64];
  __shared__ alignas(16) unsigned short Ks[64 * 64];
  __shared__ alignas(16) unsigned short VTs[64 * 64];
  __shared__ alignas(16) unsigned short Ps[4][16][72];

  const int wave = tid >> 6, lane = tid & 63;
  const int l15  = lane & 15, quad = lane >> 4;
  const int lrow = lane >> 3, lchunk = (lane & 7) ^ ((lane >> 3) & 7);
  const float C2 = 0.18033688011112042f;     // 0.125 * log2(e)

  // stage Q (128x64, 4 copies of 8 rows per wave)
  const unsigned short* gq =
      qb + ((size_t)n * T_SEQ + qtb * 128 + wave * 32 + lrow) * 512 + h * 64 + lchunk * 8;
  #pragma unroll
  for (int rr = 0; rr < 4; ++rr)
    async_copy16(gq + (size_t)(rr * 8) * 512, &Qs[(wave * 32 + rr * 8) * 64]);

  const unsigned short* gk0 =
      kb + ((size_t)n * T_SEQ + wave * 16 + lrow) * 512 + h * 64 + lchunk * 8;
  const unsigned short* gv0 =
      vt + ((size_t)n * 512 + h * 64 + wave * 16 + lrow) * 384 + lchunk * 8;

  const int nkt = 2 * qtb + 2;

  float lsum[2][4] = {};
  f32x4 oacc[2][4] = {};

  // stage K/V tile 0
  async_copy16(gk0,           &Ks[(wave * 16) * 64]);
  async_copy16(gk0 + 8 * 512, &Ks[(wave * 16 + 8) * 64]);
  async_copy16(gv0,           &VTs[(wave * 16) * 64]);
  async_copy16(gv0 + 8 * 384, &VTs[(wave * 16 + 8) * 64]);
  __syncthreads();

  // Q fragments -> registers (loop-invariant across kt)
  bf16x8 aq[2][2];
  #pragma unroll
  for (int s = 0; s < 2; ++s)
    #pragma unroll
    for (int kc = 0; kc < 2; ++kc) {
      const int pcq = ((kc * 4 + quad) ^ (l15 & 7)) * 8;
      aq[s][kc] = *reinterpret_cast<const bf16x8*>(
          &Qs[(wave * 32 + s * 16 + l15) * 64 + pcq]);
    }

  for (int kt = 0; kt < nkt; ++kt) {
    #pragma unroll
    for (int s = 0; s < 2; ++s) {
      const int qsub = qtb * 128 + wave * 32 + s * 16;   // first q-row of sub
      if (kt * 64 > qsub + 15) continue;                 // fully masked (uniform)

      // ---- S = Q K^T ----
      f32x4 sc4[4] = {};
      #pragma unroll
      for (int kc = 0; kc < 2; ++kc) {
        const int pc = ((kc * 4 + quad) ^ (l15 & 7)) * 8;
        #pragma unroll
        for (int tc = 0; tc < 4; ++tc) {
          bf16x8 bk = *reinterpret_cast<const bf16x8*>(&Ks[(tc * 16 + l15) * 64 + pc]);
          sc4[tc] = __builtin_amdgcn_mfma_f32_16x16x32_bf16(aq[s][kc], bk, sc4[tc], 0, 0, 0);
        }
      }
      // ---- fixed-max exp2 softmax + causal mask ----
      float ps_[4][4];
      #pragma unroll
      for (int tc = 0; tc < 4; ++tc)
        #pragma unroll
        for (int r = 0; r < 4; ++r) {
          float p = fast_exp2(sc4[tc][r] * C2 - 16.0f);
          int kglob = kt * 64 + tc * 16 + l15;
          int qglob = qsub + quad * 4 + r;
          if (kglob > qglob) p = 0.f;
          lsum[s][r] += p;
          ps_[tc][r] = p;
        }
      // ---- pack P (trunc->bf16) into k'-permuted LDS: k' = l15*4 + tc ----
      #pragma unroll
      for (int r = 0; r < 4; ++r) {
        union { float f; unsigned int u; } a0, a1, a2, a3;
        a0.f = ps_[0][r]; a1.f = ps_[1][r]; a2.f = ps_[2][r]; a3.f = ps_[3][r];
        uint2 pk;
        pk.x = (a1.u & 0xffff0000u) | (a0.u >> 16);
        pk.y = (a3.u & 0xffff0000u) | (a2.u >> 16);
        *reinterpret_cast<uint2*>(&Ps[wave][quad * 4 + r][l15 * 4]) = pk;
      }
      // ---- O += P V (both sides k'-permuted) ----
      #pragma unroll
      for (int kc = 0; kc < 2; ++kc) {
        const int pc = ((kc * 4 + quad) ^ (l15 & 7)) * 8;
        bf16x8 ap = *reinterpret_cast<const bf16x8*>(&Ps[wave][l15][kc * 32 + quad * 8]);
        #pragma unroll
        for (int dt = 0; dt < 4; ++dt) {
          bf16x8 bv = *reinterpret_cast<const bf16x8*>(&VTs[(dt * 16 + l15) * 64 + pc]);
          oacc[s][dt] = __builtin_amdgcn_mfma_f32_16x16x32_bf16(ap, bv, oacc[s][dt], 0, 0, 0);
        }
      }
    }
    if (kt + 1 < nkt) {
      __syncthreads();   // all waves done reading Ks/VTs
      const size_t ko = (size_t)(kt + 1) * 64;
      async_copy16(gk0 + ko * 512,                 &Ks[(wave * 16) * 64]);
      async_copy16(gk0 + (ko + 8) * 512,           &Ks[(wave * 16 + 8) * 64]);
      async_copy16(gv0 + (kt + 1) * 64,            &VTs[(wave * 16) * 64]);
      async_copy16(gv0 + (kt + 1) * 64 + 8 * 384,  &VTs[(wave * 16 + 8) * 64]);
      __syncthreads();   // staged (vmcnt drained by compiler before barrier)
    }
  }

  // ---- lsum reduce + epilogue: residual add, write y[t][n][d] ----
  float inv[2][4];
  #pragma unroll
  for (int s = 0; s < 2; ++s)
    #pragma unroll
    for (int r = 0; r < 4; ++r) {
      float l = lsum[s][r];
      l += __shfl_xor(l, 1);
      l += __shfl_xor(l, 2);
      l += __shfl_xor(l, 4);
      l += __shfl_xor(l, 8);
      inv[s][r] = 1.0f / l;
    }
  #pragma unroll
  for (int s = 0; s < 2; ++s)
    #pragma unroll
    for (int dt = 0; dt < 4; ++dt)
      #pragma unroll
      for (int r = 0; r < 4; ++r) {
        int tq = qtb * 128 + wave * 32 + s * 16 + quad * 4 + r;
        int d  = h * 64 + dt * 16 + l15;
        float val = oacc[s][dt][r] * inv[s][r];
        float res = bf2f(xt[((size_t)n * T_SEQ + tq) * 512 + d]);
        y[((size_t)tq * NNEUR + n) * 512 + d] = f2bf(val + res);
      }
}

// ------------------------------------------------------------------
extern "C" void kernel_launch(void* const* d_in, const int* in_sizes, int n_in,
                              void* d_out, int out_size, void* d_ws, size_t ws_size,
                              hipStream_t stream) {
  const float* x   = (const float*)d_in[0];
  const int*   pad = (const int*)d_in[1];
  const float* nw  = (const float*)d_in[2];
  const float* wq  = (const float*)d_in[3];
  const float* wk  = (const float*)d_in[4];
  const float* wv  = (const float*)d_in[5];
  const float* wo  = (const float*)d_in[6];
  float* out = (float*)d_out;

  char* ws = (char*)d_ws;
  size_t off = 0;
  auto alloc = [&](size_t bytes) { void* p = ws + off; off += (bytes + 255) & ~(size_t)255; return p; };
  const size_t WELEM  = (size_t)512 * 512;        // elements per weight
  const size_t MBYTES = (size_t)NROWS * 512 * 2;
  unsigned short* wqkv_bf = (unsigned short*)alloc(WELEM * 3 * 2);
  unsigned short* wo_bf   = (unsigned short*)alloc(WELEM * 2);
  float2*         rtab    = (float2*)alloc(384 * 16 * sizeof(float2));
  unsigned short* xt_bf   = (unsigned short*)alloc(MBYTES);
  unsigned short* qk_buf  = (unsigned short*)alloc(MBYTES * 2);
  unsigned short* vt_buf  = (unsigned short*)alloc(MBYTES);
  unsigned short* y_buf   = (unsigned short*)alloc(MBYTES);

  prep_kernel<<<dim3(256, 5), 256, 0, stream>>>(
      wq, wk, wv, wo,
      wqkv_bf, wqkv_bf + WELEM, wqkv_bf + 2 * WELEM, wo_bf, rtab);
  rmsnorm_kernel<<<NROWS / 4, 256, 0, stream>>>(x, nw, xt_bf);
  // fused Q|K GEMM (+RoPE): grid x = column block (8 -> n0 in [0,1024))
  gemm_k<2, unsigned short><<<dim3(8, NROWS / 128), 256, 0, stream>>>(
      xt_bf, wqkv_bf, qk_buf, rtab, pad);
  // V^T (k-permuted): A = wv (512 rows), B = xt
  gemm_k<3, unsigned short><<<dim3(4, NROWS / 128), 256, 0, stream>>>(
      wqkv_bf + 2 * WELEM, xt_bf, vt_buf, nullptr, pad);
  attn_kernel<<<dim3(3, 8, 128), 256, 0, stream>>>(
      qk_buf, qk_buf + (size_t)NROWS * 512, vt_buf, xt_bf, pad, y_buf);
  // out = y Wo^T (fp32)
  gemm_k<0, float><<<dim3(4, NROWS / 128), 256, 0, stream>>>(
      y_buf, wo_bf, out, nullptr, pad);
}

// Round 6
// 338.664 us; speedup vs baseline: 1.2733x; 1.0098x over previous
//
#include <hip/hip_runtime.h>
#include <hip/hip_bf16.h>
#include <stdint.h>

typedef __bf16 bf16x8 __attribute__((ext_vector_type(8)));
typedef float f32x4 __attribute__((ext_vector_type(4)));

static constexpr int T_SEQ  = 384;
static constexpr int NNEUR  = 128;
static constexpr int DMODEL = 512;
static constexpr int NROWS  = NNEUR * T_SEQ;   // 49152
static constexpr float ROPE_C = 0.8304820237218406f;  // log2(10000)/16

__device__ __forceinline__ float bf2f(unsigned short u) {
  union { unsigned int i; float f; } x; x.i = ((unsigned int)u) << 16; return x.f;
}
__device__ __forceinline__ unsigned short f2bf(float f) {
  union { float f; unsigned int i; } x; x.f = f;
  unsigned int i = x.i;
  i += 0x7FFFu + ((i >> 16) & 1u);   // RNE
  return (unsigned short)(i >> 16);
}
__device__ __forceinline__ float fast_exp2(float x) {
#if __has_builtin(__builtin_amdgcn_exp2f)
  return __builtin_amdgcn_exp2f(x);
#else
  return exp2f(x);
#endif
}

// async global->LDS, 16B per lane; LDS dest = wave-uniform base + lane*16
__device__ __forceinline__ void async_copy16(const unsigned short* g, unsigned short* l) {
  auto gp = reinterpret_cast<const __attribute__((address_space(1))) unsigned int*>(
      reinterpret_cast<uintptr_t>(g));
  auto lp = reinterpret_cast<__attribute__((address_space(3))) unsigned int*>(
      reinterpret_cast<uintptr_t>(l));
  __builtin_amdgcn_global_load_lds(gp, lp, 16, 0, 0);
}

// ------------------------------------------------------------------
// prep: weights fp32 -> bf16 (y=0..3) + rope table (y=4)
// tab[t*16+i] = (sin, cos) of t * 10000^(-i/16)
// ------------------------------------------------------------------
__global__ __launch_bounds__(256) void prep_kernel(
    const float* __restrict__ w0, const float* __restrict__ w1,
    const float* __restrict__ w2, const float* __restrict__ w3,
    unsigned short* __restrict__ o0, unsigned short* __restrict__ o1,
    unsigned short* __restrict__ o2, unsigned short* __restrict__ o3,
    float2* __restrict__ tab)
{
  if (blockIdx.y == 4) {
    if (blockIdx.x >= 24) return;
    int idx = blockIdx.x * 256 + threadIdx.x;   // 6144
    int t = idx >> 4, i = idx & 15;
    float ang = (float)t * exp2f(-(float)i * ROPE_C);
    float s, c; sincosf(ang, &s, &c);
    tab[idx] = make_float2(s, c);
    return;
  }
  const float* w; unsigned short* o;
  switch (blockIdx.y) {
    case 0:  w = w0; o = o0; break;
    case 1:  w = w1; o = o1; break;
    case 2:  w = w2; o = o2; break;
    default: w = w3; o = o3; break;
  }
  int i = (blockIdx.x * 256 + threadIdx.x) * 4;
  float4 v = *reinterpret_cast<const float4*>(w + i);
  union { unsigned short u[4]; uint2 v2; } p;
  p.u[0] = f2bf(v.x); p.u[1] = f2bf(v.y); p.u[2] = f2bf(v.z); p.u[3] = f2bf(v.w);
  *reinterpret_cast<uint2*>(o + i) = p.v2;
}

// ------------------------------------------------------------------
// RMSNorm: x[t][n][d] fp32 -> xt_bf[n][t][d] bf16 (also the residual)
// ------------------------------------------------------------------
__global__ __launch_bounds__(256) void rmsnorm_kernel(
    const float* __restrict__ x, const float* __restrict__ nw,
    unsigned short* __restrict__ xt)
{
  int wave = threadIdx.x >> 6, lane = threadIdx.x & 63;
  int rid = blockIdx.x * 4 + wave;       // rid = t*128 + n
  int t = rid >> 7, n = rid & 127;
  const float* row = x + (size_t)rid * DMODEL;
  float4 v0 = *reinterpret_cast<const float4*>(row + lane * 8);
  float4 v1 = *reinterpret_cast<const float4*>(row + lane * 8 + 4);
  float ss = v0.x*v0.x + v0.y*v0.y + v0.z*v0.z + v0.w*v0.w
           + v1.x*v1.x + v1.y*v1.y + v1.z*v1.z + v1.w*v1.w;
  #pragma unroll
  for (int off = 32; off; off >>= 1) ss += __shfl_xor(ss, off);
  float sc = rsqrtf(ss * (1.0f / DMODEL) + 1e-6f);
  float4 w0 = *reinterpret_cast<const float4*>(nw + lane * 8);
  float4 w1 = *reinterpret_cast<const float4*>(nw + lane * 8 + 4);
  union { unsigned short u[8]; uint4 v; } p;
  p.u[0] = f2bf(v0.x * sc * w0.x); p.u[1] = f2bf(v0.y * sc * w0.y);
  p.u[2] = f2bf(v0.z * sc * w0.z); p.u[3] = f2bf(v0.w * sc * w0.w);
  p.u[4] = f2bf(v1.x * sc * w1.x); p.u[5] = f2bf(v1.y * sc * w1.y);
  p.u[6] = f2bf(v1.z * sc * w1.z); p.u[7] = f2bf(v1.w * sc * w1.w);
  *reinterpret_cast<uint4*>(xt + ((size_t)n * T_SEQ + t) * DMODEL + lane * 8) = p.v;
}

// ------------------------------------------------------------------
// GEMM: D[m][n] = sum_k A[m][k]*B[n][k], bf16 in, fp32 acc.
// 128x128 tile, 256 threads / 4 waves (2m x 2n, 64x64 per wave).
// BK=32, THREE LDS buffers (48 KiB -> 3 blocks/CU), depth-2 counted
// vmcnt pipeline: steady state keeps 2 stages (8 loads) in flight
// across barriers, waiting vmcnt(8) -- never draining to 0 until the
// tail. Load latency is covered by ~2 compute phases + 12-wave TLP.
// T5 setprio around the MFMA cluster. XCD-aware chunked block swizzle.
// Exact pad-mask skip (128-row tiles lie in one neuron).
// MODE 0: fp32 row-major store (out = y Wo^T)
// MODE 2: bf16 row-major store + table RoPE; C covers q|k sections (n0>>9)
// MODE 3: bf16 transposed + k-permuted store -> vt[nn][dout][kperm(t)]
// ------------------------------------------------------------------
template <int MODE, typename OutT>
__global__ __launch_bounds__(256, 3) void gemm_k(
    const unsigned short* __restrict__ A,
    const unsigned short* __restrict__ B,
    OutT* __restrict__ C,
    const float2* __restrict__ tab,
    const int* __restrict__ pad)
{
  // per buffer: A[128][32] (4096 elems) + B[128][32] (4096) = 16 KiB
  __shared__ alignas(16) unsigned short Sh[3][8192];
  const int tid  = threadIdx.x;
  const int wave = tid >> 6, lane = tid & 63;
  const int l15  = lane & 15, quad = lane >> 4;
  const int wm = (wave >> 1) * 64, wn = (wave & 1) * 64;

  // XCD-aware chunked swizzle (bijective: NB % 8 == 0, chunk % GX == 0)
  constexpr int GX = (MODE == 2) ? 8 : 4;
  constexpr int GY = 384;
  constexpr int NB = GX * GY;
  constexpr int CH = NB / 8;
  const int lin = (int)blockIdx.y * GX + (int)blockIdx.x;
  const int swz = (lin & 7) * CH + (lin >> 3);
  const int bx  = swz % GX, by = swz / GX;

  size_t m0; int n0;
  if constexpr (MODE == 3) { m0 = (size_t)bx * 128; n0 = by * 128; }
  else                     { m0 = (size_t)by * 128; n0 = bx * 128; }

  // dead-tile skip (wave-uniform); 128-row/col tiles lie in ONE neuron
  if constexpr (MODE == 2) {
    if (pad[(int)(m0 / 384)] == 0) return;
  }
  if constexpr (MODE == 3) {
    if (pad[n0 / 384] == 0) return;
  }

  // staging geometry: row r = tid>>2 (0..63, +64 for 2nd copy), chunk tid&3
  const int r = tid >> 2;
  const int gc = (tid & 3) ^ (r & 3);      // swizzled global chunk
  const unsigned short* ga = A + (m0 + r) * 512 + gc * 8;
  const unsigned short* gb = B + ((size_t)n0 + r) * 512 + gc * 8;

  // LDS->frag chunk (unswizzle): row = ..+l15 so row&3 == l15&3
  const int pc = (quad ^ (l15 & 3)) * 8;

  auto STAGE = [&](int kk, int b) {
    const unsigned short* gak = ga + kk * 32;
    const unsigned short* gbk = gb + kk * 32;
    unsigned short* base = &Sh[b][0] + tid * 8;
    async_copy16(gak,            base);              // A rows 0-63
    async_copy16(gak + 64 * 512, base + 2048);       // A rows 64-127
    async_copy16(gbk,            base + 4096);       // B rows 0-63
    async_copy16(gbk + 64 * 512, base + 4096 + 2048);// B rows 64-127
  };

  f32x4 acc[4][4] = {};
  auto COMPUTE = [&](int b) {
    const unsigned short* base = &Sh[b][0];
    bf16x8 a[4], bb[4];
    #pragma unroll
    for (int i = 0; i < 4; ++i)
      a[i] = *reinterpret_cast<const bf16x8*>(&base[(wm + i * 16 + l15) * 32 + pc]);
    #pragma unroll
    for (int j = 0; j < 4; ++j)
      bb[j] = *reinterpret_cast<const bf16x8*>(&base[4096 + (wn + j * 16 + l15) * 32 + pc]);
    __builtin_amdgcn_s_setprio(1);
    #pragma unroll
    for (int i = 0; i < 4; ++i)
      #pragma unroll
      for (int j = 0; j < 4; ++j)
        acc[i][j] = __builtin_amdgcn_mfma_f32_16x16x32_bf16(a[i], bb[j], acc[i][j], 0, 0, 0);
    __builtin_amdgcn_s_setprio(0);
  };

  // depth-2 pipeline over 16 K-tiles of 32
  STAGE(0, 0);
  STAGE(1, 1);
  #pragma unroll
  for (int t = 0; t < 14; ++t) {
    STAGE(t + 2, (t + 2) % 3);
    asm volatile("s_waitcnt vmcnt(8)" ::: "memory");  // stage t landed
    __builtin_amdgcn_s_barrier();
    COMPUTE(t % 3);
    __builtin_amdgcn_s_barrier();                     // buf (t%3) free for re-stage
  }
  asm volatile("s_waitcnt vmcnt(4)" ::: "memory");    // stage 14 landed
  __builtin_amdgcn_s_barrier();
  COMPUTE(14 % 3);
  asm volatile("s_waitcnt vmcnt(0)" ::: "memory");    // stage 15 landed
  __builtin_amdgcn_s_barrier();
  COMPUTE(15 % 3);

  // ---- epilogue ----
  if constexpr (MODE == 3) {
    // element: (dout = m-row, xtrow = n-col). store vt[nn][dout][kperm(t)]
    #pragma unroll
    for (int j = 0; j < 4; ++j) {
      int xbase = n0 + wn + j * 16;            // multiple of 16
      int nn    = xbase / 384;
      int bloc  = xbase - nn * 384;
      int off64 = (bloc >> 6) * 64 + ((bloc >> 4) & 3);   // + l15*4 gives k'
      #pragma unroll
      for (int i = 0; i < 4; ++i)
        #pragma unroll
        for (int r2 = 0; r2 < 4; ++r2) {
          int dout = (int)m0 + wm + i * 16 + quad * 4 + r2;
          C[((size_t)nn * 512 + dout) * 384 + off64 + l15 * 4] = f2bf(acc[i][j][r2]);
        }
    }
  } else {
    OutT* Cb = C;
    int ncol0 = n0 + wn;
    if constexpr (MODE == 2) {
      int sec = n0 >> 9;                        // 0=q, 1=k (tiles don't straddle 512)
      Cb = C + (size_t)sec * NROWS * 512;
      ncol0 = (n0 & 511) + wn;
    }
    #pragma unroll
    for (int i = 0; i < 4; ++i) {
      #pragma unroll
      for (int r2 = 0; r2 < 4; ++r2) {
        size_t grow = m0 + wm + i * 16 + quad * 4 + r2;
        int t = (int)(grow % 384);
        #pragma unroll
        for (int j = 0; j < 4; ++j) {
          float v = acc[i][j][r2];
          int col = ncol0 + j * 16 + l15;
          if constexpr (MODE == 2) {
            if (((ncol0 + j * 16) & 63) < 32) {   // rotary half (wave-uniform)
              float part = __shfl_xor(v, 1);
              float2 scv = tab[t * 16 + ((col & 63) >> 1)];
              v = (l15 & 1) ? (part * scv.x + v * scv.y)
                            : (v * scv.y - part * scv.x);
            }
            Cb[grow * 512 + col] = f2bf(v);
          } else {
            Cb[grow * 512 + col] = v;   // fp32
          }
        }
      }
    }
  }
}

// ------------------------------------------------------------------
// Flash attention, QBLK=128. Q/K pre-RoPE'd; V pre-transposed AND
// k-permuted (vt[n][d][k'], k' = (t&15)*4 + (t>>4) within each 64-tile).
// Each block: 128 q-rows (4 waves x 32 rows = 2 sub-tiles of 16).
// Q fragments hoisted to registers (loop-invariant).
// Fixed-max exp2 softmax; always-on causal compare; wave-uniform skip
// of fully-masked sub-tiles. Invalid neurons (pad==0): y = residual.
// ------------------------------------------------------------------
__global__ __launch_bounds__(256, 4) void attn_kernel(
    const unsigned short* __restrict__ qb,   // [n][t][512]
    const unsigned short* __restrict__ kb,   // [n][t][512]
    const unsigned short* __restrict__ vt,   // [n][512][384] (k-permuted)
    const unsigned short* __restrict__ xt,   // residual [n][t][512]
    const int* __restrict__ pad,             // [128]
    unsigned short* __restrict__ y)          // [t][n][512]
{
  // grid = (3, 8, 128) -> 3072 blocks; chunk = 384 (divisible by 3)
  const int lin = (int)blockIdx.x + 3 * ((int)blockIdx.y + 8 * (int)blockIdx.z);
  const int swz = (lin & 7) * 384 + (lin >> 3);
  const int qtb = swz % 3;          // 0..2 (128 q-rows each)
  const int rem = swz / 3;
  const int h   = rem & 7;          // 0..7
  const int n   = rem >> 3;         // 0..127

  const int tid  = threadIdx.x;

  if (pad[n] == 0) {
    // y = residual only (bf16 copy is exact). 128 rows x 64 cols.
    int rb = tid >> 2;
    int d  = h * 64 + (tid & 3) * 16;
    #pragma unroll
    for (int rr = 0; rr < 128; rr += 64) {
      int tq = qtb * 128 + rr + rb;
      const uint4* src = reinterpret_cast<const uint4*>(
          &xt[((size_t)n * T_SEQ + tq) * 512 + d]);
      uint4* dst = reinterpret_cast<uint4*>(
          &y[((size_t)tq * NNEUR + n) * 512 + d]);
      dst[0] = src[0];
      dst[1] = src[1];
    }
    return;
  }

  __shared__ alignas(16) unsigned short Qs[128 * 64];
  __shared__ alignas(16) unsigned short Ks[64 * 64];
  __shared__ alignas(16) unsigned short VTs[64 * 64];
  __shared__ alignas(16) unsigned short Ps[4][16][72];

  const int wave = tid >> 6, lane = tid & 63;
  const int l15  = lane & 15, quad = lane >> 4;
  const int lrow = lane >> 3, lchunk = (lane & 7) ^ ((lane >> 3) & 7);
  const float C2 = 0.18033688011112042f;     // 0.125 * log2(e)

  // stage Q (128x64, 4 copies of 8 rows per wave)
  const unsigned short* gq =
      qb + ((size_t)n * T_SEQ + qtb * 128 + wave * 32 + lrow) * 512 + h * 64 + lchunk * 8;
  #pragma unroll
  for (int rr = 0; rr < 4; ++rr)
    async_copy16(gq + (size_t)(rr * 8) * 512, &Qs[(wave * 32 + rr * 8) * 64]);

  const unsigned short* gk0 =
      kb + ((size_t)n * T_SEQ + wave * 16 + lrow) * 512 + h * 64 + lchunk * 8;
  const unsigned short* gv0 =
      vt + ((size_t)n * 512 + h * 64 + wave * 16 + lrow) * 384 + lchunk * 8;

  const int nkt = 2 * qtb + 2;

  float lsum[2][4] = {};
  f32x4 oacc[2][4] = {};

  // stage K/V tile 0
  async_copy16(gk0,           &Ks[(wave * 16) * 64]);
  async_copy16(gk0 + 8 * 512, &Ks[(wave * 16 + 8) * 64]);
  async_copy16(gv0,           &VTs[(wave * 16) * 64]);
  async_copy16(gv0 + 8 * 384, &VTs[(wave * 16 + 8) * 64]);
  __syncthreads();

  // Q fragments -> registers (loop-invariant across kt)
  bf16x8 aq[2][2];
  #pragma unroll
  for (int s = 0; s < 2; ++s)
    #pragma unroll
    for (int kc = 0; kc < 2; ++kc) {
      const int pcq = ((kc * 4 + quad) ^ (l15 & 7)) * 8;
      aq[s][kc] = *reinterpret_cast<const bf16x8*>(
          &Qs[(wave * 32 + s * 16 + l15) * 64 + pcq]);
    }

  for (int kt = 0; kt < nkt; ++kt) {
    #pragma unroll
    for (int s = 0; s < 2; ++s) {
      const int qsub = qtb * 128 + wave * 32 + s * 16;   // first q-row of sub
      if (kt * 64 > qsub + 15) continue;                 // fully masked (uniform)

      // ---- S = Q K^T ----
      f32x4 sc4[4] = {};
      #pragma unroll
      for (int kc = 0; kc < 2; ++kc) {
        const int pc = ((kc * 4 + quad) ^ (l15 & 7)) * 8;
        #pragma unroll
        for (int tc = 0; tc < 4; ++tc) {
          bf16x8 bk = *reinterpret_cast<const bf16x8*>(&Ks[(tc * 16 + l15) * 64 + pc]);
          sc4[tc] = __builtin_amdgcn_mfma_f32_16x16x32_bf16(aq[s][kc], bk, sc4[tc], 0, 0, 0);
        }
      }
      // ---- fixed-max exp2 softmax + causal mask ----
      float ps_[4][4];
      #pragma unroll
      for (int tc = 0; tc < 4; ++tc)
        #pragma unroll
        for (int r = 0; r < 4; ++r) {
          float p = fast_exp2(sc4[tc][r] * C2 - 16.0f);
          int kglob = kt * 64 + tc * 16 + l15;
          int qglob = qsub + quad * 4 + r;
          if (kglob > qglob) p = 0.f;
          lsum[s][r] += p;
          ps_[tc][r] = p;
        }
      // ---- pack P (trunc->bf16) into k'-permuted LDS: k' = l15*4 + tc ----
      #pragma unroll
      for (int r = 0; r < 4; ++r) {
        union { float f; unsigned int u; } a0, a1, a2, a3;
        a0.f = ps_[0][r]; a1.f = ps_[1][r]; a2.f = ps_[2][r]; a3.f = ps_[3][r];
        uint2 pk;
        pk.x = (a1.u & 0xffff0000u) | (a0.u >> 16);
        pk.y = (a3.u & 0xffff0000u) | (a2.u >> 16);
        *reinterpret_cast<uint2*>(&Ps[wave][quad * 4 + r][l15 * 4]) = pk;
      }
      // ---- O += P V (both sides k'-permuted) ----
      #pragma unroll
      for (int kc = 0; kc < 2; ++kc) {
        const int pc = ((kc * 4 + quad) ^ (l15 & 7)) * 8;
        bf16x8 ap = *reinterpret_cast<const bf16x8*>(&Ps[wave][l15][kc * 32 + quad * 8]);
        #pragma unroll
        for (int dt = 0; dt < 4; ++dt) {
          bf16x8 bv = *reinterpret_cast<const bf16x8*>(&VTs[(dt * 16 + l15) * 64 + pc]);
          oacc[s][dt] = __builtin_amdgcn_mfma_f32_16x16x32_bf16(ap, bv, oacc[s][dt], 0, 0, 0);
        }
      }
    }
    if (kt + 1 < nkt) {
      __syncthreads();   // all waves done reading Ks/VTs
      const size_t ko = (size_t)(kt + 1) * 64;
      async_copy16(gk0 + ko * 512,                 &Ks[(wave * 16) * 64]);
      async_copy16(gk0 + (ko + 8) * 512,           &Ks[(wave * 16 + 8) * 64]);
      async_copy16(gv0 + (kt + 1) * 64,            &VTs[(wave * 16) * 64]);
      async_copy16(gv0 + (kt + 1) * 64 + 8 * 384,  &VTs[(wave * 16 + 8) * 64]);
      __syncthreads();   // staged (vmcnt drained by compiler before barrier)
    }
  }

  // ---- lsum reduce + epilogue: residual add, write y[t][n][d] ----
  float inv[2][4];
  #pragma unroll
  for (int s = 0; s < 2; ++s)
    #pragma unroll
    for (int r = 0; r < 4; ++r) {
      float l = lsum[s][r];
      l += __shfl_xor(l, 1);
      l += __shfl_xor(l, 2);
      l += __shfl_xor(l, 4);
      l += __shfl_xor(l, 8);
      inv[s][r] = 1.0f / l;
    }
  #pragma unroll
  for (int s = 0; s < 2; ++s)
    #pragma unroll
    for (int dt = 0; dt < 4; ++dt)
      #pragma unroll
      for (int r = 0; r < 4; ++r) {
        int tq = qtb * 128 + wave * 32 + s * 16 + quad * 4 + r;
        int d  = h * 64 + dt * 16 + l15;
        float val = oacc[s][dt][r] * inv[s][r];
        float res = bf2f(xt[((size_t)n * T_SEQ + tq) * 512 + d]);
        y[((size_t)tq * NNEUR + n) * 512 + d] = f2bf(val + res);
      }
}

// ------------------------------------------------------------------
extern "C" void kernel_launch(void* const* d_in, const int* in_sizes, int n_in,
                              void* d_out, int out_size, void* d_ws, size_t ws_size,
                              hipStream_t stream) {
  const float* x   = (const float*)d_in[0];
  const int*   pad = (const int*)d_in[1];
  const float* nw  = (const float*)d_in[2];
  const float* wq  = (const float*)d_in[3];
  const float* wk  = (const float*)d_in[4];
  const float* wv  = (const float*)d_in[5];
  const float* wo  = (const float*)d_in[6];
  float* out = (float*)d_out;

  char* ws = (char*)d_ws;
  size_t off = 0;
  auto alloc = [&](size_t bytes) { void* p = ws + off; off += (bytes + 255) & ~(size_t)255; return p; };
  const size_t WELEM  = (size_t)512 * 512;        // elements per weight
  const size_t MBYTES = (size_t)NROWS * 512 * 2;
  unsigned short* wqkv_bf = (unsigned short*)alloc(WELEM * 3 * 2);
  unsigned short* wo_bf   = (unsigned short*)alloc(WELEM * 2);
  float2*         rtab    = (float2*)alloc(384 * 16 * sizeof(float2));
  unsigned short* xt_bf   = (unsigned short*)alloc(MBYTES);
  unsigned short* qk_buf  = (unsigned short*)alloc(MBYTES * 2);
  unsigned short* vt_buf  = (unsigned short*)alloc(MBYTES);
  unsigned short* y_buf   = (unsigned short*)alloc(MBYTES);

  prep_kernel<<<dim3(256, 5), 256, 0, stream>>>(
      wq, wk, wv, wo,
      wqkv_bf, wqkv_bf + WELEM, wqkv_bf + 2 * WELEM, wo_bf, rtab);
  rmsnorm_kernel<<<NROWS / 4, 256, 0, stream>>>(x, nw, xt_bf);
  // fused Q|K GEMM (+RoPE): grid x = column block (8 -> n0 in [0,1024))
  gemm_k<2, unsigned short><<<dim3(8, NROWS / 128), 256, 0, stream>>>(
      xt_bf, wqkv_bf, qk_buf, rtab, pad);
  // V^T (k-permuted): A = wv (512 rows), B = xt
  gemm_k<3, unsigned short><<<dim3(4, NROWS / 128), 256, 0, stream>>>(
      wqkv_bf + 2 * WELEM, xt_bf, vt_buf, nullptr, pad);
  attn_kernel<<<dim3(3, 8, 128), 256, 0, stream>>>(
      qk_buf, qk_buf + (size_t)NROWS * 512, vt_buf, xt_bf, pad, y_buf);
  // out = y Wo^T (fp32)
  gemm_k<0, float><<<dim3(4, NROWS / 128), 256, 0, stream>>>(
      y_buf, wo_bf, out, nullptr, pad);
}

// Round 7
// 325.944 us; speedup vs baseline: 1.3230x; 1.0390x over previous
//
#include <hip/hip_runtime.h>
#include <hip/hip_bf16.h>
#include <stdint.h>

typedef __bf16 bf16x8 __attribute__((ext_vector_type(8)));
typedef float f32x4 __attribute__((ext_vector_type(4)));

static constexpr int T_SEQ  = 384;
static constexpr int NNEUR  = 128;
static constexpr int DMODEL = 512;
static constexpr int NROWS  = NNEUR * T_SEQ;   // 49152
static constexpr float ROPE_C = 0.8304820237218406f;  // log2(10000)/16

__device__ __forceinline__ float bf2f(unsigned short u) {
  union { unsigned int i; float f; } x; x.i = ((unsigned int)u) << 16; return x.f;
}
__device__ __forceinline__ unsigned short f2bf(float f) {
  union { float f; unsigned int i; } x; x.f = f;
  unsigned int i = x.i;
  i += 0x7FFFu + ((i >> 16) & 1u);   // RNE
  return (unsigned short)(i >> 16);
}
__device__ __forceinline__ float fast_exp2(float x) {
#if __has_builtin(__builtin_amdgcn_exp2f)
  return __builtin_amdgcn_exp2f(x);
#else
  return exp2f(x);
#endif
}

// async global->LDS, 16B per lane; LDS dest = wave-uniform base + lane*16
__device__ __forceinline__ void async_copy16(const unsigned short* g, unsigned short* l) {
  auto gp = reinterpret_cast<const __attribute__((address_space(1))) unsigned int*>(
      reinterpret_cast<uintptr_t>(g));
  auto lp = reinterpret_cast<__attribute__((address_space(3))) unsigned int*>(
      reinterpret_cast<uintptr_t>(l));
  __builtin_amdgcn_global_load_lds(gp, lp, 16, 0, 0);
}

// ------------------------------------------------------------------
// fused pre: RMSNorm (ids < 12288) + weight cvt (next 1024) + rope (24)
// RMSNorm: x[t][n][d] fp32 -> xt_bf[n][t][d] bf16 (also the residual)
// tab[t*16+i] = (sin, cos) of t * 10000^(-i/16)
// ------------------------------------------------------------------
__global__ __launch_bounds__(256) void pre_kernel(
    const float* __restrict__ x, const float* __restrict__ nw,
    unsigned short* __restrict__ xt,
    const float* __restrict__ w0, const float* __restrict__ w1,
    const float* __restrict__ w2, const float* __restrict__ w3,
    unsigned short* __restrict__ o0, unsigned short* __restrict__ o1,
    unsigned short* __restrict__ o2, unsigned short* __restrict__ o3,
    float2* __restrict__ tab)
{
  const int id = blockIdx.x;
  if (id < 12288) {
    int wave = threadIdx.x >> 6, lane = threadIdx.x & 63;
    int rid = id * 4 + wave;       // rid = t*128 + n
    int t = rid >> 7, n = rid & 127;
    const float* row = x + (size_t)rid * DMODEL;
    float4 v0 = *reinterpret_cast<const float4*>(row + lane * 8);
    float4 v1 = *reinterpret_cast<const float4*>(row + lane * 8 + 4);
    float ss = v0.x*v0.x + v0.y*v0.y + v0.z*v0.z + v0.w*v0.w
             + v1.x*v1.x + v1.y*v1.y + v1.z*v1.z + v1.w*v1.w;
    #pragma unroll
    for (int off = 32; off; off >>= 1) ss += __shfl_xor(ss, off);
    float sc = rsqrtf(ss * (1.0f / DMODEL) + 1e-6f);
    float4 w0v = *reinterpret_cast<const float4*>(nw + lane * 8);
    float4 w1v = *reinterpret_cast<const float4*>(nw + lane * 8 + 4);
    union { unsigned short u[8]; uint4 v; } p;
    p.u[0] = f2bf(v0.x * sc * w0v.x); p.u[1] = f2bf(v0.y * sc * w0v.y);
    p.u[2] = f2bf(v0.z * sc * w0v.z); p.u[3] = f2bf(v0.w * sc * w0v.w);
    p.u[4] = f2bf(v1.x * sc * w1v.x); p.u[5] = f2bf(v1.y * sc * w1v.y);
    p.u[6] = f2bf(v1.z * sc * w1v.z); p.u[7] = f2bf(v1.w * sc * w1v.w);
    *reinterpret_cast<uint4*>(xt + ((size_t)n * T_SEQ + t) * DMODEL + lane * 8) = p.v;
    return;
  }
  int e = id - 12288;
  if (e < 1024) {
    const float* w; unsigned short* o;
    switch (e >> 8) {
      case 0:  w = w0; o = o0; break;
      case 1:  w = w1; o = o1; break;
      case 2:  w = w2; o = o2; break;
      default: w = w3; o = o3; break;
    }
    int i = ((e & 255) * 256 + threadIdx.x) * 4;
    float4 v = *reinterpret_cast<const float4*>(w + i);
    union { unsigned short u[4]; uint2 v2; } p;
    p.u[0] = f2bf(v.x); p.u[1] = f2bf(v.y); p.u[2] = f2bf(v.z); p.u[3] = f2bf(v.w);
    *reinterpret_cast<uint2*>(o + i) = p.v2;
    return;
  }
  int e2 = e - 1024;                           // 0..23
  int idx = e2 * 256 + threadIdx.x;            // 6144
  int t = idx >> 4, i = idx & 15;
  float ang = (float)t * exp2f(-(float)i * ROPE_C);
  float s, c; sincosf(ang, &s, &c);
  tab[idx] = make_float2(s, c);
}

// ------------------------------------------------------------------
// GEMM body: D[m][n] = sum_k A[m][k]*B[n][k], bf16 in, fp32 acc.
// 128x128 tile, 256 threads / 4 waves (2m x 2n, 64x64 per wave).
// BK=32, THREE LDS buffers, depth-2 counted vmcnt pipeline (vmcnt(8)
// steady state, never 0 until tail). T5 setprio around MFMA cluster.
// MODE 0: fp32 row-major store (out = y Wo^T)
// MODE 2: bf16 row-major store + table RoPE; C covers q|k sections (n0>>9)
// MODE 3: bf16 transposed + k-permuted store -> vt[nn][dout][kperm(t)]
// ------------------------------------------------------------------
template <int MODE, typename OutT>
__device__ __forceinline__ void gemm_body(
    const unsigned short* __restrict__ A,
    const unsigned short* __restrict__ B,
    OutT* __restrict__ C,
    const float2* __restrict__ tab,
    int bx, int by,
    unsigned short (&Sh)[3][8192])
{
  const int tid  = threadIdx.x;
  const int wave = tid >> 6, lane = tid & 63;
  const int l15  = lane & 15, quad = lane >> 4;
  const int wm = (wave >> 1) * 64, wn = (wave & 1) * 64;

  size_t m0; int n0;
  if constexpr (MODE == 3) { m0 = (size_t)bx * 128; n0 = by * 128; }
  else                     { m0 = (size_t)by * 128; n0 = bx * 128; }

  // staging geometry: row r = tid>>2 (0..63, +64 for 2nd copy), chunk tid&3
  const int r = tid >> 2;
  const int gc = (tid & 3) ^ (r & 3);      // swizzled global chunk
  const unsigned short* ga = A + (m0 + r) * 512 + gc * 8;
  const unsigned short* gb = B + ((size_t)n0 + r) * 512 + gc * 8;

  // LDS->frag chunk (unswizzle): row = ..+l15 so row&3 == l15&3
  const int pc = (quad ^ (l15 & 3)) * 8;

  auto STAGE = [&](int kk, int b) {
    const unsigned short* gak = ga + kk * 32;
    const unsigned short* gbk = gb + kk * 32;
    unsigned short* base = &Sh[b][0] + tid * 8;
    async_copy16(gak,            base);              // A rows 0-63
    async_copy16(gak + 64 * 512, base + 2048);       // A rows 64-127
    async_copy16(gbk,            base + 4096);       // B rows 0-63
    async_copy16(gbk + 64 * 512, base + 4096 + 2048);// B rows 64-127
  };

  f32x4 acc[4][4] = {};
  auto COMPUTE = [&](int b) {
    const unsigned short* base = &Sh[b][0];
    bf16x8 a[4], bb[4];
    #pragma unroll
    for (int i = 0; i < 4; ++i)
      a[i] = *reinterpret_cast<const bf16x8*>(&base[(wm + i * 16 + l15) * 32 + pc]);
    #pragma unroll
    for (int j = 0; j < 4; ++j)
      bb[j] = *reinterpret_cast<const bf16x8*>(&base[4096 + (wn + j * 16 + l15) * 32 + pc]);
    __builtin_amdgcn_s_setprio(1);
    #pragma unroll
    for (int i = 0; i < 4; ++i)
      #pragma unroll
      for (int j = 0; j < 4; ++j)
        acc[i][j] = __builtin_amdgcn_mfma_f32_16x16x32_bf16(a[i], bb[j], acc[i][j], 0, 0, 0);
    __builtin_amdgcn_s_setprio(0);
  };

  // depth-2 pipeline over 16 K-tiles of 32
  STAGE(0, 0);
  STAGE(1, 1);
  #pragma unroll
  for (int t = 0; t < 14; ++t) {
    STAGE(t + 2, (t + 2) % 3);
    asm volatile("s_waitcnt vmcnt(8)" ::: "memory");  // stage t landed
    __builtin_amdgcn_s_barrier();
    COMPUTE(t % 3);
    __builtin_amdgcn_s_barrier();                     // buf (t%3) free for re-stage
  }
  asm volatile("s_waitcnt vmcnt(4)" ::: "memory");    // stage 14 landed
  __builtin_amdgcn_s_barrier();
  COMPUTE(14 % 3);
  asm volatile("s_waitcnt vmcnt(0)" ::: "memory");    // stage 15 landed
  __builtin_amdgcn_s_barrier();
  COMPUTE(15 % 3);

  // ---- epilogue ----
  if constexpr (MODE == 3) {
    // element: (dout = m-row, xtrow = n-col). store vt[nn][dout][kperm(t)]
    #pragma unroll
    for (int j = 0; j < 4; ++j) {
      int xbase = n0 + wn + j * 16;            // multiple of 16
      int nn    = xbase / 384;
      int bloc  = xbase - nn * 384;
      int off64 = (bloc >> 6) * 64 + ((bloc >> 4) & 3);   // + l15*4 gives k'
      #pragma unroll
      for (int i = 0; i < 4; ++i)
        #pragma unroll
        for (int r2 = 0; r2 < 4; ++r2) {
          int dout = (int)m0 + wm + i * 16 + quad * 4 + r2;
          C[((size_t)nn * 512 + dout) * 384 + off64 + l15 * 4] = f2bf(acc[i][j][r2]);
        }
    }
  } else {
    OutT* Cb = C;
    int ncol0 = n0 + wn;
    if constexpr (MODE == 2) {
      int sec = n0 >> 9;                        // 0=q, 1=k (tiles don't straddle 512)
      Cb = C + (size_t)sec * NROWS * 512;
      ncol0 = (n0 & 511) + wn;
    }
    #pragma unroll
    for (int i = 0; i < 4; ++i) {
      #pragma unroll
      for (int r2 = 0; r2 < 4; ++r2) {
        size_t grow = m0 + wm + i * 16 + quad * 4 + r2;
        int t = (int)(grow % 384);
        #pragma unroll
        for (int j = 0; j < 4; ++j) {
          float v = acc[i][j][r2];
          int col = ncol0 + j * 16 + l15;
          if constexpr (MODE == 2) {
            if (((ncol0 + j * 16) & 63) < 32) {   // rotary half (wave-uniform)
              float part = __shfl_xor(v, 1);
              float2 scv = tab[t * 16 + ((col & 63) >> 1)];
              v = (l15 & 1) ? (part * scv.x + v * scv.y)
                            : (v * scv.y - part * scv.x);
            }
            Cb[grow * 512 + col] = f2bf(v);
          } else {
            Cb[grow * 512 + col] = v;   // fp32
          }
        }
      }
    }
  }
}

// ------------------------------------------------------------------
// fused QKV GEMM dispatch: blocks [0,3072) = MODE2 (Q|K + RoPE),
// blocks [3072,4608) = MODE3 (V^T k-permuted). Both read xt/weights
// only -> independent; fusing absorbs MODE3 into MODE2's tail.
// XCD swizzle per sub-range (3072 % 8 == 0 so local lin%8 == XCD).
// Exact pad-mask skip (128-row/col tiles lie in one neuron).
// ------------------------------------------------------------------
__global__ __launch_bounds__(256, 3) void gemm_qkv(
    const unsigned short* __restrict__ xt,
    const unsigned short* __restrict__ wqkv,   // wq|wk|wv rows stacked
    unsigned short* __restrict__ qk,           // [2][NROWS][512]
    unsigned short* __restrict__ vt,           // [n][512][384] k-permuted
    const float2* __restrict__ tab,
    const int* __restrict__ pad)
{
  __shared__ alignas(16) unsigned short Sh[3][8192];
  const int lin = (int)blockIdx.x;
  if (lin < 3072) {
    // MODE2: GX=8, GY=384, CH=384
    const int swz = (lin & 7) * 384 + (lin >> 3);
    const int bx = swz & 7, by = swz >> 3;
    if (pad[(by * 128) / 384] == 0) return;
    gemm_body<2, unsigned short>(xt, wqkv, qk, tab, bx, by, Sh);
  } else {
    // MODE3: GX=4, GY=384, CH=192
    const int l = lin - 3072;
    const int swz = (l & 7) * 192 + (l >> 3);
    const int bx = swz & 3, by = swz >> 2;
    if (pad[(by * 128) / 384] == 0) return;
    gemm_body<3, unsigned short>(wqkv + (size_t)2 * 512 * 512, xt, vt,
                                 nullptr, bx, by, Sh);
  }
}

// out = y Wo^T (fp32). GX=4, GY=384, CH=192.
__global__ __launch_bounds__(256, 3) void gemm_out(
    const unsigned short* __restrict__ y,
    const unsigned short* __restrict__ wo,
    float* __restrict__ out)
{
  __shared__ alignas(16) unsigned short Sh[3][8192];
  const int lin = (int)blockIdx.x;
  const int swz = (lin & 7) * 192 + (lin >> 3);
  const int bx = swz & 3, by = swz >> 2;
  gemm_body<0, float>(y, wo, out, nullptr, bx, by, Sh);
}

// ------------------------------------------------------------------
// Flash attention, QBLK=128. Q/K pre-RoPE'd; V pre-transposed AND
// k-permuted (vt[n][d][k'], k' = (t&15)*4 + (t>>4) within each 64-tile).
// Each block: 128 q-rows (4 waves x 32 rows = 2 sub-tiles of 16).
// Q fragments hoisted to registers (loop-invariant).
// Fixed-max exp2 softmax; always-on causal compare; wave-uniform skip
// of fully-masked sub-tiles. Invalid neurons (pad==0): y = residual.
// ------------------------------------------------------------------
__global__ __launch_bounds__(256, 4) void attn_kernel(
    const unsigned short* __restrict__ qb,   // [n][t][512]
    const unsigned short* __restrict__ kb,   // [n][t][512]
    const unsigned short* __restrict__ vt,   // [n][512][384] (k-permuted)
    const unsigned short* __restrict__ xt,   // residual [n][t][512]
    const int* __restrict__ pad,             // [128]
    unsigned short* __restrict__ y)          // [t][n][512]
{
  // grid = (3, 8, 128) -> 3072 blocks; chunk = 384 (divisible by 3)
  const int lin = (int)blockIdx.x + 3 * ((int)blockIdx.y + 8 * (int)blockIdx.z);
  const int swz = (lin & 7) * 384 + (lin >> 3);
  const int qtb = swz % 3;          // 0..2 (128 q-rows each)
  const int rem = swz / 3;
  const int h   = rem & 7;          // 0..7
  const int n   = rem >> 3;         // 0..127

  const int tid  = threadIdx.x;

  if (pad[n] == 0) {
    // y = residual only (bf16 copy is exact). 128 rows x 64 cols.
    int rb = tid >> 2;
    int d  = h * 64 + (tid & 3) * 16;
    #pragma unroll
    for (int rr = 0; rr < 128; rr += 64) {
      int tq = qtb * 128 + rr + rb;
      const uint4* src = reinterpret_cast<const uint4*>(
          &xt[((size_t)n * T_SEQ + tq) * 512 + d]);
      uint4* dst = reinterpret_cast<uint4*>(
          &y[((size_t)tq * NNEUR + n) * 512 + d]);
      dst[0] = src[0];
      dst[1] = src[1];
    }
    return;
  }

  __shared__ alignas(16) unsigned short Qs[128 * 64];
  __shared__ alignas(16) unsigned short Ks[64 * 64];
  __shared__ alignas(16) unsigned short VTs[64 * 64];
  __shared__ alignas(16) unsigned short Ps[4][16][72];

  const int wave = tid >> 6, lane = tid & 63;
  const int l15  = lane & 15, quad = lane >> 4;
  const int lrow = lane >> 3, lchunk = (lane & 7) ^ ((lane >> 3) & 7);
  const float C2 = 0.18033688011112042f;     // 0.125 * log2(e)

  // stage Q (128x64, 4 copies of 8 rows per wave)
  const unsigned short* gq =
      qb + ((size_t)n * T_SEQ + qtb * 128 + wave * 32 + lrow) * 512 + h * 64 + lchunk * 8;
  #pragma unroll
  for (int rr = 0; rr < 4; ++rr)
    async_copy16(gq + (size_t)(rr * 8) * 512, &Qs[(wave * 32 + rr * 8) * 64]);

  const unsigned short* gk0 =
      kb + ((size_t)n * T_SEQ + wave * 16 + lrow) * 512 + h * 64 + lchunk * 8;
  const unsigned short* gv0 =
      vt + ((size_t)n * 512 + h * 64 + wave * 16 + lrow) * 384 + lchunk * 8;

  const int nkt = 2 * qtb + 2;

  float lsum[2][4] = {};
  f32x4 oacc[2][4] = {};

  // stage K/V tile 0
  async_copy16(gk0,           &Ks[(wave * 16) * 64]);
  async_copy16(gk0 + 8 * 512, &Ks[(wave * 16 + 8) * 64]);
  async_copy16(gv0,           &VTs[(wave * 16) * 64]);
  async_copy16(gv0 + 8 * 384, &VTs[(wave * 16 + 8) * 64]);
  __syncthreads();

  // Q fragments -> registers (loop-invariant across kt)
  bf16x8 aq[2][2];
  #pragma unroll
  for (int s = 0; s < 2; ++s)
    #pragma unroll
    for (int kc = 0; kc < 2; ++kc) {
      const int pcq = ((kc * 4 + quad) ^ (l15 & 7)) * 8;
      aq[s][kc] = *reinterpret_cast<const bf16x8*>(
          &Qs[(wave * 32 + s * 16 + l15) * 64 + pcq]);
    }

  for (int kt = 0; kt < nkt; ++kt) {
    #pragma unroll
    for (int s = 0; s < 2; ++s) {
      const int qsub = qtb * 128 + wave * 32 + s * 16;   // first q-row of sub
      if (kt * 64 > qsub + 15) continue;                 // fully masked (uniform)

      // ---- S = Q K^T ----
      f32x4 sc4[4] = {};
      #pragma unroll
      for (int kc = 0; kc < 2; ++kc) {
        const int pc = ((kc * 4 + quad) ^ (l15 & 7)) * 8;
        #pragma unroll
        for (int tc = 0; tc < 4; ++tc) {
          bf16x8 bk = *reinterpret_cast<const bf16x8*>(&Ks[(tc * 16 + l15) * 64 + pc]);
          sc4[tc] = __builtin_amdgcn_mfma_f32_16x16x32_bf16(aq[s][kc], bk, sc4[tc], 0, 0, 0);
        }
      }
      // ---- fixed-max exp2 softmax + causal mask ----
      float ps_[4][4];
      #pragma unroll
      for (int tc = 0; tc < 4; ++tc)
        #pragma unroll
        for (int r = 0; r < 4; ++r) {
          float p = fast_exp2(sc4[tc][r] * C2 - 16.0f);
          int kglob = kt * 64 + tc * 16 + l15;
          int qglob = qsub + quad * 4 + r;
          if (kglob > qglob) p = 0.f;
          lsum[s][r] += p;
          ps_[tc][r] = p;
        }
      // ---- pack P (trunc->bf16) into k'-permuted LDS: k' = l15*4 + tc ----
      #pragma unroll
      for (int r = 0; r < 4; ++r) {
        union { float f; unsigned int u; } a0, a1, a2, a3;
        a0.f = ps_[0][r]; a1.f = ps_[1][r]; a2.f = ps_[2][r]; a3.f = ps_[3][r];
        uint2 pk;
        pk.x = (a1.u & 0xffff0000u) | (a0.u >> 16);
        pk.y = (a3.u & 0xffff0000u) | (a2.u >> 16);
        *reinterpret_cast<uint2*>(&Ps[wave][quad * 4 + r][l15 * 4]) = pk;
      }
      // ---- O += P V (both sides k'-permuted) ----
      #pragma unroll
      for (int kc = 0; kc < 2; ++kc) {
        const int pc = ((kc * 4 + quad) ^ (l15 & 7)) * 8;
        bf16x8 ap = *reinterpret_cast<const bf16x8*>(&Ps[wave][l15][kc * 32 + quad * 8]);
        #pragma unroll
        for (int dt = 0; dt < 4; ++dt) {
          bf16x8 bv = *reinterpret_cast<const bf16x8*>(&VTs[(dt * 16 + l15) * 64 + pc]);
          oacc[s][dt] = __builtin_amdgcn_mfma_f32_16x16x32_bf16(ap, bv, oacc[s][dt], 0, 0, 0);
        }
      }
    }
    if (kt + 1 < nkt) {
      __syncthreads();   // all waves done reading Ks/VTs
      const size_t ko = (size_t)(kt + 1) * 64;
      async_copy16(gk0 + ko * 512,                 &Ks[(wave * 16) * 64]);
      async_copy16(gk0 + (ko + 8) * 512,           &Ks[(wave * 16 + 8) * 64]);
      async_copy16(gv0 + (kt + 1) * 64,            &VTs[(wave * 16) * 64]);
      async_copy16(gv0 + (kt + 1) * 64 + 8 * 384,  &VTs[(wave * 16 + 8) * 64]);
      __syncthreads();   // staged (vmcnt drained by compiler before barrier)
    }
  }

  // ---- lsum reduce + epilogue: residual add, write y[t][n][d] ----
  float inv[2][4];
  #pragma unroll
  for (int s = 0; s < 2; ++s)
    #pragma unroll
    for (int r = 0; r < 4; ++r) {
      float l = lsum[s][r];
      l += __shfl_xor(l, 1);
      l += __shfl_xor(l, 2);
      l += __shfl_xor(l, 4);
      l += __shfl_xor(l, 8);
      inv[s][r] = 1.0f / l;
    }
  #pragma unroll
  for (int s = 0; s < 2; ++s)
    #pragma unroll
    for (int dt = 0; dt < 4; ++dt)
      #pragma unroll
      for (int r = 0; r < 4; ++r) {
        int tq = qtb * 128 + wave * 32 + s * 16 + quad * 4 + r;
        int d  = h * 64 + dt * 16 + l15;
        float val = oacc[s][dt][r] * inv[s][r];
        float res = bf2f(xt[((size_t)n * T_SEQ + tq) * 512 + d]);
        y[((size_t)tq * NNEUR + n) * 512 + d] = f2bf(val + res);
      }
}

// ------------------------------------------------------------------
extern "C" void kernel_launch(void* const* d_in, const int* in_sizes, int n_in,
                              void* d_out, int out_size, void* d_ws, size_t ws_size,
                              hipStream_t stream) {
  const float* x   = (const float*)d_in[0];
  const int*   pad = (const int*)d_in[1];
  const float* nw  = (const float*)d_in[2];
  const float* wq  = (const float*)d_in[3];
  const float* wk  = (const float*)d_in[4];
  const float* wv  = (const float*)d_in[5];
  const float* wo  = (const float*)d_in[6];
  float* out = (float*)d_out;

  char* ws = (char*)d_ws;
  size_t off = 0;
  auto alloc = [&](size_t bytes) { void* p = ws + off; off += (bytes + 255) & ~(size_t)255; return p; };
  const size_t WELEM  = (size_t)512 * 512;        // elements per weight
  const size_t MBYTES = (size_t)NROWS * 512 * 2;
  unsigned short* wqkv_bf = (unsigned short*)alloc(WELEM * 3 * 2);
  unsigned short* wo_bf   = (unsigned short*)alloc(WELEM * 2);
  float2*         rtab    = (float2*)alloc(384 * 16 * sizeof(float2));
  unsigned short* xt_bf   = (unsigned short*)alloc(MBYTES);
  unsigned short* qk_buf  = (unsigned short*)alloc(MBYTES * 2);
  unsigned short* vt_buf  = (unsigned short*)alloc(MBYTES);
  unsigned short* y_buf   = (unsigned short*)alloc(MBYTES);

  // fused rmsnorm + weight cvt + rope table
  pre_kernel<<<12288 + 1024 + 24, 256, 0, stream>>>(
      x, nw, xt_bf,
      wq, wk, wv, wo,
      wqkv_bf, wqkv_bf + WELEM, wqkv_bf + 2 * WELEM, wo_bf, rtab);
  // fused Q|K GEMM (+RoPE) and V^T GEMM in one dispatch
  gemm_qkv<<<3072 + 1536, 256, 0, stream>>>(
      xt_bf, wqkv_bf, qk_buf, vt_buf, rtab, pad);
  attn_kernel<<<dim3(3, 8, 128), 256, 0, stream>>>(
      qk_buf, qk_buf + (size_t)NROWS * 512, vt_buf, xt_bf, pad, y_buf);
  // out = y Wo^T (fp32)
  gemm_out<<<1536, 256, 0, stream>>>(y_buf, wo_bf, out);
}

// Round 8
// 322.301 us; speedup vs baseline: 1.3379x; 1.0113x over previous
//
#include <hip/hip_runtime.h>
#include <hip/hip_bf16.h>
#include <stdint.h>

typedef __bf16 bf16x8 __attribute__((ext_vector_type(8)));
typedef float f32x4 __attribute__((ext_vector_type(4)));

static constexpr int T_SEQ  = 384;
static constexpr int NNEUR  = 128;
static constexpr int DMODEL = 512;
static constexpr int NROWS  = NNEUR * T_SEQ;   // 49152
static constexpr float ROPE_C = 0.8304820237218406f;  // log2(10000)/16

__device__ __forceinline__ float bf2f(unsigned short u) {
  union { unsigned int i; float f; } x; x.i = ((unsigned int)u) << 16; return x.f;
}
__device__ __forceinline__ unsigned short f2bf(float f) {
  union { float f; unsigned int i; } x; x.f = f;
  unsigned int i = x.i;
  i += 0x7FFFu + ((i >> 16) & 1u);   // RNE
  return (unsigned short)(i >> 16);
}
__device__ __forceinline__ float fast_exp2(float x) {
#if __has_builtin(__builtin_amdgcn_exp2f)
  return __builtin_amdgcn_exp2f(x);
#else
  return exp2f(x);
#endif
}

// async global->LDS, 16B per lane; LDS dest = wave-uniform base + lane*16
__device__ __forceinline__ void async_copy16(const unsigned short* g, unsigned short* l) {
  auto gp = reinterpret_cast<const __attribute__((address_space(1))) unsigned int*>(
      reinterpret_cast<uintptr_t>(g));
  auto lp = reinterpret_cast<__attribute__((address_space(3))) unsigned int*>(
      reinterpret_cast<uintptr_t>(l));
  __builtin_amdgcn_global_load_lds(gp, lp, 16, 0, 0);
}

// ------------------------------------------------------------------
// fused pre: RMSNorm (ids < 12288) + weight cvt (next 1024) + rope (24)
// RMSNorm: x[t][n][d] fp32 -> xt_bf[n][t][d] bf16 (also the residual)
// tab[t*16+i] = (sin, cos) of t * 10000^(-i/16)
// ------------------------------------------------------------------
__global__ __launch_bounds__(256) void pre_kernel(
    const float* __restrict__ x, const float* __restrict__ nw,
    unsigned short* __restrict__ xt,
    const float* __restrict__ w0, const float* __restrict__ w1,
    const float* __restrict__ w2, const float* __restrict__ w3,
    unsigned short* __restrict__ o0, unsigned short* __restrict__ o1,
    unsigned short* __restrict__ o2, unsigned short* __restrict__ o3,
    float2* __restrict__ tab)
{
  const int id = blockIdx.x;
  if (id < 12288) {
    int wave = threadIdx.x >> 6, lane = threadIdx.x & 63;
    int rid = id * 4 + wave;       // rid = t*128 + n
    int t = rid >> 7, n = rid & 127;
    const float* row = x + (size_t)rid * DMODEL;
    float4 v0 = *reinterpret_cast<const float4*>(row + lane * 8);
    float4 v1 = *reinterpret_cast<const float4*>(row + lane * 8 + 4);
    float ss = v0.x*v0.x + v0.y*v0.y + v0.z*v0.z + v0.w*v0.w
             + v1.x*v1.x + v1.y*v1.y + v1.z*v1.z + v1.w*v1.w;
    #pragma unroll
    for (int off = 32; off; off >>= 1) ss += __shfl_xor(ss, off);
    float sc = rsqrtf(ss * (1.0f / DMODEL) + 1e-6f);
    float4 w0v = *reinterpret_cast<const float4*>(nw + lane * 8);
    float4 w1v = *reinterpret_cast<const float4*>(nw + lane * 8 + 4);
    union { unsigned short u[8]; uint4 v; } p;
    p.u[0] = f2bf(v0.x * sc * w0v.x); p.u[1] = f2bf(v0.y * sc * w0v.y);
    p.u[2] = f2bf(v0.z * sc * w0v.z); p.u[3] = f2bf(v0.w * sc * w0v.w);
    p.u[4] = f2bf(v1.x * sc * w1v.x); p.u[5] = f2bf(v1.y * sc * w1v.y);
    p.u[6] = f2bf(v1.z * sc * w1v.z); p.u[7] = f2bf(v1.w * sc * w1v.w);
    *reinterpret_cast<uint4*>(xt + ((size_t)n * T_SEQ + t) * DMODEL + lane * 8) = p.v;
    return;
  }
  int e = id - 12288;
  if (e < 1024) {
    const float* w; unsigned short* o;
    switch (e >> 8) {
      case 0:  w = w0; o = o0; break;
      case 1:  w = w1; o = o1; break;
      case 2:  w = w2; o = o2; break;
      default: w = w3; o = o3; break;
    }
    int i = ((e & 255) * 256 + threadIdx.x) * 4;
    float4 v = *reinterpret_cast<const float4*>(w + i);
    union { unsigned short u[4]; uint2 v2; } p;
    p.u[0] = f2bf(v.x); p.u[1] = f2bf(v.y); p.u[2] = f2bf(v.z); p.u[3] = f2bf(v.w);
    *reinterpret_cast<uint2*>(o + i) = p.v2;
    return;
  }
  int e2 = e - 1024;                           // 0..23
  int idx = e2 * 256 + threadIdx.x;            // 6144
  int t = idx >> 4, i = idx & 15;
  float ang = (float)t * exp2f(-(float)i * ROPE_C);
  float s, c; sincosf(ang, &s, &c);
  tab[idx] = make_float2(s, c);
}

// ------------------------------------------------------------------
// GEMM body: D[m][n] = sum_k A[m][k]*B[n][k], bf16 in, fp32 acc.
// 128x128 tile, 256 threads / 4 waves (2m x 2n, 64x64 per wave).
// BK=32, THREE LDS buffers, depth-2 counted vmcnt pipeline (vmcnt(8)
// steady state, never 0 until tail). T5 setprio around MFMA cluster.
// LDS chunk swizzle uses (l15>>1)&3 so each 16-lane phase covers all
// 8 (row-parity x chunk) bank groups 2x -> conflict-free b128 reads
// (the l15&3 variant was a measured 4.9M-cycle bank conflict, R7).
// MODE 0: fp32 row-major store (out = y Wo^T)
// MODE 2: bf16 row-major store + table RoPE; C covers q|k sections (n0>>9)
// MODE 3: bf16 transposed + k-permuted store -> vt[nn][dout][kperm(t)]
// ------------------------------------------------------------------
template <int MODE, typename OutT>
__device__ __forceinline__ void gemm_body(
    const unsigned short* __restrict__ A,
    const unsigned short* __restrict__ B,
    OutT* __restrict__ C,
    const float2* __restrict__ tab,
    int bx, int by,
    unsigned short (&Sh)[3][8192])
{
  const int tid  = threadIdx.x;
  const int wave = tid >> 6, lane = tid & 63;
  const int l15  = lane & 15, quad = lane >> 4;
  const int wm = (wave >> 1) * 64, wn = (wave & 1) * 64;

  size_t m0; int n0;
  if constexpr (MODE == 3) { m0 = (size_t)bx * 128; n0 = by * 128; }
  else                     { m0 = (size_t)by * 128; n0 = bx * 128; }

  // staging geometry: row r = tid>>2 (0..63, +64 for 2nd copy), chunk tid&3
  const int r = tid >> 2;
  const int gc = (tid & 3) ^ ((r >> 1) & 3);   // swizzled global chunk
  const unsigned short* ga = A + (m0 + r) * 512 + gc * 8;
  const unsigned short* gb = B + ((size_t)n0 + r) * 512 + gc * 8;

  // LDS->frag chunk (unswizzle): row = ..+l15, (row>>1)&3 == (l15>>1)&3
  const int pc = (quad ^ ((l15 >> 1) & 3)) * 8;

  auto STAGE = [&](int kk, int b) {
    const unsigned short* gak = ga + kk * 32;
    const unsigned short* gbk = gb + kk * 32;
    unsigned short* base = &Sh[b][0] + tid * 8;
    async_copy16(gak,            base);              // A rows 0-63
    async_copy16(gak + 64 * 512, base + 2048);       // A rows 64-127
    async_copy16(gbk,            base + 4096);       // B rows 0-63
    async_copy16(gbk + 64 * 512, base + 4096 + 2048);// B rows 64-127
  };

  f32x4 acc[4][4] = {};
  auto COMPUTE = [&](int b) {
    const unsigned short* base = &Sh[b][0];
    bf16x8 a[4], bb[4];
    #pragma unroll
    for (int i = 0; i < 4; ++i)
      a[i] = *reinterpret_cast<const bf16x8*>(&base[(wm + i * 16 + l15) * 32 + pc]);
    #pragma unroll
    for (int j = 0; j < 4; ++j)
      bb[j] = *reinterpret_cast<const bf16x8*>(&base[4096 + (wn + j * 16 + l15) * 32 + pc]);
    __builtin_amdgcn_s_setprio(1);
    #pragma unroll
    for (int i = 0; i < 4; ++i)
      #pragma unroll
      for (int j = 0; j < 4; ++j)
        acc[i][j] = __builtin_amdgcn_mfma_f32_16x16x32_bf16(a[i], bb[j], acc[i][j], 0, 0, 0);
    __builtin_amdgcn_s_setprio(0);
  };

  // depth-2 pipeline over 16 K-tiles of 32
  STAGE(0, 0);
  STAGE(1, 1);
  #pragma unroll
  for (int t = 0; t < 14; ++t) {
    STAGE(t + 2, (t + 2) % 3);
    asm volatile("s_waitcnt vmcnt(8)" ::: "memory");  // stage t landed
    __builtin_amdgcn_s_barrier();
    COMPUTE(t % 3);
    __builtin_amdgcn_s_barrier();                     // buf (t%3) free for re-stage
  }
  asm volatile("s_waitcnt vmcnt(4)" ::: "memory");    // stage 14 landed
  __builtin_amdgcn_s_barrier();
  COMPUTE(14 % 3);
  asm volatile("s_waitcnt vmcnt(0)" ::: "memory");    // stage 15 landed
  __builtin_amdgcn_s_barrier();
  COMPUTE(15 % 3);

  // ---- epilogue ----
  if constexpr (MODE == 3) {
    // element: (dout = m-row, xtrow = n-col). store vt[nn][dout][kperm(t)]
    #pragma unroll
    for (int j = 0; j < 4; ++j) {
      int xbase = n0 + wn + j * 16;            // multiple of 16
      int nn    = xbase / 384;
      int bloc  = xbase - nn * 384;
      int off64 = (bloc >> 6) * 64 + ((bloc >> 4) & 3);   // + l15*4 gives k'
      #pragma unroll
      for (int i = 0; i < 4; ++i)
        #pragma unroll
        for (int r2 = 0; r2 < 4; ++r2) {
          int dout = (int)m0 + wm + i * 16 + quad * 4 + r2;
          C[((size_t)nn * 512 + dout) * 384 + off64 + l15 * 4] = f2bf(acc[i][j][r2]);
        }
    }
  } else {
    OutT* Cb = C;
    int ncol0 = n0 + wn;
    if constexpr (MODE == 2) {
      int sec = n0 >> 9;                        // 0=q, 1=k (tiles don't straddle 512)
      Cb = C + (size_t)sec * NROWS * 512;
      ncol0 = (n0 & 511) + wn;
    }
    #pragma unroll
    for (int i = 0; i < 4; ++i) {
      #pragma unroll
      for (int r2 = 0; r2 < 4; ++r2) {
        size_t grow = m0 + wm + i * 16 + quad * 4 + r2;
        int t = (int)(grow % 384);
        #pragma unroll
        for (int j = 0; j < 4; ++j) {
          float v = acc[i][j][r2];
          int col = ncol0 + j * 16 + l15;
          if constexpr (MODE == 2) {
            if (((ncol0 + j * 16) & 63) < 32) {   // rotary half (wave-uniform)
              float part = __shfl_xor(v, 1);
              float2 scv = tab[t * 16 + ((col & 63) >> 1)];
              v = (l15 & 1) ? (part * scv.x + v * scv.y)
                            : (v * scv.y - part * scv.x);
            }
            Cb[grow * 512 + col] = f2bf(v);
          } else {
            Cb[grow * 512 + col] = v;   // fp32
          }
        }
      }
    }
  }
}

// ------------------------------------------------------------------
// fused QKV GEMM dispatch: blocks [0,3072) = MODE2 (Q|K + RoPE),
// blocks [3072,4608) = MODE3 (V^T k-permuted). Both read xt/weights
// only -> independent; fusing absorbs MODE3 into MODE2's tail.
// XCD swizzle per sub-range (3072 % 8 == 0 so local lin%8 == XCD).
// Exact pad-mask skip (128-row/col tiles lie in one neuron).
// ------------------------------------------------------------------
__global__ __launch_bounds__(256, 3) void gemm_qkv(
    const unsigned short* __restrict__ xt,
    const unsigned short* __restrict__ wqkv,   // wq|wk|wv rows stacked
    unsigned short* __restrict__ qk,           // [2][NROWS][512]
    unsigned short* __restrict__ vt,           // [n][512][384] k-permuted
    const float2* __restrict__ tab,
    const int* __restrict__ pad)
{
  __shared__ alignas(16) unsigned short Sh[3][8192];
  const int lin = (int)blockIdx.x;
  if (lin < 3072) {
    // MODE2: GX=8, GY=384, CH=384
    const int swz = (lin & 7) * 384 + (lin >> 3);
    const int bx = swz & 7, by = swz >> 3;
    if (pad[(by * 128) / 384] == 0) return;
    gemm_body<2, unsigned short>(xt, wqkv, qk, tab, bx, by, Sh);
  } else {
    // MODE3: GX=4, GY=384, CH=192
    const int l = lin - 3072;
    const int swz = (l & 7) * 192 + (l >> 3);
    const int bx = swz & 3, by = swz >> 2;
    if (pad[(by * 128) / 384] == 0) return;
    gemm_body<3, unsigned short>(wqkv + (size_t)2 * 512 * 512, xt, vt,
                                 nullptr, bx, by, Sh);
  }
}

// out = y Wo^T (fp32). GX=4, GY=384, CH=192.
__global__ __launch_bounds__(256, 3) void gemm_out(
    const unsigned short* __restrict__ y,
    const unsigned short* __restrict__ wo,
    float* __restrict__ out)
{
  __shared__ alignas(16) unsigned short Sh[3][8192];
  const int lin = (int)blockIdx.x;
  const int swz = (lin & 7) * 192 + (lin >> 3);
  const int bx = swz & 3, by = swz >> 2;
  gemm_body<0, float>(y, wo, out, nullptr, bx, by, Sh);
}

// ------------------------------------------------------------------
// Flash attention, QBLK=128. Q/K pre-RoPE'd; V pre-transposed AND
// k-permuted (vt[n][d][k'], k' = (t&15)*4 + (t>>4) within each 64-tile).
// Each block: 128 q-rows (4 waves x 32 rows = 2 sub-tiles of 16).
// Q fragments hoisted to registers (loop-invariant).
// Fixed-max exp2 softmax; always-on causal compare; wave-uniform skip
// of fully-masked sub-tiles. Invalid neurons (pad==0): y = residual.
// ------------------------------------------------------------------
__global__ __launch_bounds__(256, 4) void attn_kernel(
    const unsigned short* __restrict__ qb,   // [n][t][512]
    const unsigned short* __restrict__ kb,   // [n][t][512]
    const unsigned short* __restrict__ vt,   // [n][512][384] (k-permuted)
    const unsigned short* __restrict__ xt,   // residual [n][t][512]
    const int* __restrict__ pad,             // [128]
    unsigned short* __restrict__ y)          // [t][n][512]
{
  // grid = (3, 8, 128) -> 3072 blocks; chunk = 384 (divisible by 3)
  const int lin = (int)blockIdx.x + 3 * ((int)blockIdx.y + 8 * (int)blockIdx.z);
  const int swz = (lin & 7) * 384 + (lin >> 3);
  const int qtb = swz % 3;          // 0..2 (128 q-rows each)
  const int rem = swz / 3;
  const int h   = rem & 7;          // 0..7
  const int n   = rem >> 3;         // 0..127

  const int tid  = threadIdx.x;

  if (pad[n] == 0) {
    // y = residual only (bf16 copy is exact). 128 rows x 64 cols.
    int rb = tid >> 2;
    int d  = h * 64 + (tid & 3) * 16;
    #pragma unroll
    for (int rr = 0; rr < 128; rr += 64) {
      int tq = qtb * 128 + rr + rb;
      const uint4* src = reinterpret_cast<const uint4*>(
          &xt[((size_t)n * T_SEQ + tq) * 512 + d]);
      uint4* dst = reinterpret_cast<uint4*>(
          &y[((size_t)tq * NNEUR + n) * 512 + d]);
      dst[0] = src[0];
      dst[1] = src[1];
    }
    return;
  }

  __shared__ alignas(16) unsigned short Qs[128 * 64];
  __shared__ alignas(16) unsigned short Ks[64 * 64];
  __shared__ alignas(16) unsigned short VTs[64 * 64];
  __shared__ alignas(16) unsigned short Ps[4][16][72];

  const int wave = tid >> 6, lane = tid & 63;
  const int l15  = lane & 15, quad = lane >> 4;
  const int lrow = lane >> 3, lchunk = (lane & 7) ^ ((lane >> 3) & 7);
  const float C2 = 0.18033688011112042f;     // 0.125 * log2(e)

  // stage Q (128x64, 4 copies of 8 rows per wave)
  const unsigned short* gq =
      qb + ((size_t)n * T_SEQ + qtb * 128 + wave * 32 + lrow) * 512 + h * 64 + lchunk * 8;
  #pragma unroll
  for (int rr = 0; rr < 4; ++rr)
    async_copy16(gq + (size_t)(rr * 8) * 512, &Qs[(wave * 32 + rr * 8) * 64]);

  const unsigned short* gk0 =
      kb + ((size_t)n * T_SEQ + wave * 16 + lrow) * 512 + h * 64 + lchunk * 8;
  const unsigned short* gv0 =
      vt + ((size_t)n * 512 + h * 64 + wave * 16 + lrow) * 384 + lchunk * 8;

  const int nkt = 2 * qtb + 2;

  float lsum[2][4] = {};
  f32x4 oacc[2][4] = {};

  // stage K/V tile 0
  async_copy16(gk0,           &Ks[(wave * 16) * 64]);
  async_copy16(gk0 + 8 * 512, &Ks[(wave * 16 + 8) * 64]);
  async_copy16(gv0,           &VTs[(wave * 16) * 64]);
  async_copy16(gv0 + 8 * 384, &VTs[(wave * 16 + 8) * 64]);
  __syncthreads();

  // Q fragments -> registers (loop-invariant across kt)
  bf16x8 aq[2][2];
  #pragma unroll
  for (int s = 0; s < 2; ++s)
    #pragma unroll
    for (int kc = 0; kc < 2; ++kc) {
      const int pcq = ((kc * 4 + quad) ^ (l15 & 7)) * 8;
      aq[s][kc] = *reinterpret_cast<const bf16x8*>(
          &Qs[(wave * 32 + s * 16 + l15) * 64 + pcq]);
    }

  for (int kt = 0; kt < nkt; ++kt) {
    #pragma unroll
    for (int s = 0; s < 2; ++s) {
      const int qsub = qtb * 128 + wave * 32 + s * 16;   // first q-row of sub
      if (kt * 64 > qsub + 15) continue;                 // fully masked (uniform)

      // ---- S = Q K^T ----
      f32x4 sc4[4] = {};
      #pragma unroll
      for (int kc = 0; kc < 2; ++kc) {
        const int pc = ((kc * 4 + quad) ^ (l15 & 7)) * 8;
        #pragma unroll
        for (int tc = 0; tc < 4; ++tc) {
          bf16x8 bk = *reinterpret_cast<const bf16x8*>(&Ks[(tc * 16 + l15) * 64 + pc]);
          sc4[tc] = __builtin_amdgcn_mfma_f32_16x16x32_bf16(aq[s][kc], bk, sc4[tc], 0, 0, 0);
        }
      }
      // ---- fixed-max exp2 softmax + causal mask ----
      float ps_[4][4];
      #pragma unroll
      for (int tc = 0; tc < 4; ++tc)
        #pragma unroll
        for (int r = 0; r < 4; ++r) {
          float p = fast_exp2(sc4[tc][r] * C2 - 16.0f);
          int kglob = kt * 64 + tc * 16 + l15;
          int qglob = qsub + quad * 4 + r;
          if (kglob > qglob) p = 0.f;
          lsum[s][r] += p;
          ps_[tc][r] = p;
        }
      // ---- pack P (trunc->bf16) into k'-permuted LDS: k' = l15*4 + tc ----
      #pragma unroll
      for (int r = 0; r < 4; ++r) {
        union { float f; unsigned int u; } a0, a1, a2, a3;
        a0.f = ps_[0][r]; a1.f = ps_[1][r]; a2.f = ps_[2][r]; a3.f = ps_[3][r];
        uint2 pk;
        pk.x = (a1.u & 0xffff0000u) | (a0.u >> 16);
        pk.y = (a3.u & 0xffff0000u) | (a2.u >> 16);
        *reinterpret_cast<uint2*>(&Ps[wave][quad * 4 + r][l15 * 4]) = pk;
      }
      // ---- O += P V (both sides k'-permuted) ----
      #pragma unroll
      for (int kc = 0; kc < 2; ++kc) {
        const int pc = ((kc * 4 + quad) ^ (l15 & 7)) * 8;
        bf16x8 ap = *reinterpret_cast<const bf16x8*>(&Ps[wave][l15][kc * 32 + quad * 8]);
        #pragma unroll
        for (int dt = 0; dt < 4; ++dt) {
          bf16x8 bv = *reinterpret_cast<const bf16x8*>(&VTs[(dt * 16 + l15) * 64 + pc]);
          oacc[s][dt] = __builtin_amdgcn_mfma_f32_16x16x32_bf16(ap, bv, oacc[s][dt], 0, 0, 0);
        }
      }
    }
    if (kt + 1 < nkt) {
      __syncthreads();   // all waves done reading Ks/VTs
      const size_t ko = (size_t)(kt + 1) * 64;
      async_copy16(gk0 + ko * 512,                 &Ks[(wave * 16) * 64]);
      async_copy16(gk0 + (ko + 8) * 512,           &Ks[(wave * 16 + 8) * 64]);
      async_copy16(gv0 + (kt + 1) * 64,            &VTs[(wave * 16) * 64]);
      async_copy16(gv0 + (kt + 1) * 64 + 8 * 384,  &VTs[(wave * 16 + 8) * 64]);
      __syncthreads();   // staged (vmcnt drained by compiler before barrier)
    }
  }

  // ---- lsum reduce + epilogue: residual add, write y[t][n][d] ----
  float inv[2][4];
  #pragma unroll
  for (int s = 0; s < 2; ++s)
    #pragma unroll
    for (int r = 0; r < 4; ++r) {
      float l = lsum[s][r];
      l += __shfl_xor(l, 1);
      l += __shfl_xor(l, 2);
      l += __shfl_xor(l, 4);
      l += __shfl_xor(l, 8);
      inv[s][r] = 1.0f / l;
    }
  #pragma unroll
  for (int s = 0; s < 2; ++s)
    #pragma unroll
    for (int dt = 0; dt < 4; ++dt)
      #pragma unroll
      for (int r = 0; r < 4; ++r) {
        int tq = qtb * 128 + wave * 32 + s * 16 + quad * 4 + r;
        int d  = h * 64 + dt * 16 + l15;
        float val = oacc[s][dt][r] * inv[s][r];
        float res = bf2f(xt[((size_t)n * T_SEQ + tq) * 512 + d]);
        y[((size_t)tq * NNEUR + n) * 512 + d] = f2bf(val + res);
      }
}

// ------------------------------------------------------------------
extern "C" void kernel_launch(void* const* d_in, const int* in_sizes, int n_in,
                              void* d_out, int out_size, void* d_ws, size_t ws_size,
                              hipStream_t stream) {
  const float* x   = (const float*)d_in[0];
  const int*   pad = (const int*)d_in[1];
  const float* nw  = (const float*)d_in[2];
  const float* wq  = (const float*)d_in[3];
  const float* wk  = (const float*)d_in[4];
  const float* wv  = (const float*)d_in[5];
  const float* wo  = (const float*)d_in[6];
  float* out = (float*)d_out;

  char* ws = (char*)d_ws;
  size_t off = 0;
  auto alloc = [&](size_t bytes) { void* p = ws + off; off += (bytes + 255) & ~(size_t)255; return p; };
  const size_t WELEM  = (size_t)512 * 512;        // elements per weight
  const size_t MBYTES = (size_t)NROWS * 512 * 2;
  unsigned short* wqkv_bf = (unsigned short*)alloc(WELEM * 3 * 2);
  unsigned short* wo_bf   = (unsigned short*)alloc(WELEM * 2);
  float2*         rtab    = (float2*)alloc(384 * 16 * sizeof(float2));
  unsigned short* xt_bf   = (unsigned short*)alloc(MBYTES);
  unsigned short* qk_buf  = (unsigned short*)alloc(MBYTES * 2);
  unsigned short* vt_buf  = (unsigned short*)alloc(MBYTES);
  unsigned short* y_buf   = (unsigned short*)alloc(MBYTES);

  // fused rmsnorm + weight cvt + rope table
  pre_kernel<<<12288 + 1024 + 24, 256, 0, stream>>>(
      x, nw, xt_bf,
      wq, wk, wv, wo,
      wqkv_bf, wqkv_bf + WELEM, wqkv_bf + 2 * WELEM, wo_bf, rtab);
  // fused Q|K GEMM (+RoPE) and V^T GEMM in one dispatch
  gemm_qkv<<<3072 + 1536, 256, 0, stream>>>(
      xt_bf, wqkv_bf, qk_buf, vt_buf, rtab, pad);
  attn_kernel<<<dim3(3, 8, 128), 256, 0, stream>>>(
      qk_buf, qk_buf + (size_t)NROWS * 512, vt_buf, xt_bf, pad, y_buf);
  // out = y Wo^T (fp32)
  gemm_out<<<1536, 256, 0, stream>>>(y_buf, wo_bf, out);
}